// Round 2
// baseline (734.809 us; speedup 1.0000x reference)
//
#include <hip/hip_runtime.h>
#include <hip/hip_bf16.h>

typedef float f32x4 __attribute__((ext_vector_type(4)));
typedef __bf16 bf16x8 __attribute__((ext_vector_type(8)));

// ---- constants: B=4, S=1024, dim=2048, H=16, D=128, T=1024, KV=2048, M=4096
#define DIMK 2048
#define QSCALE ((float)(0.08838834764831845 * 1.4426950408889634))  // 1/sqrt(128)*log2(e)

__device__ __forceinline__ unsigned short f2bf(float f) {
    union { float f; unsigned int u; } v; v.f = f;
    unsigned int r = v.u + 0x7fffu + ((v.u >> 16) & 1u);
    return (unsigned short)(r >> 16);
}

// ---------------- cache copy: k_cache/v_cache -> d_out k/v regions (fp32) ----------------
__global__ __launch_bounds__(256) void copy_cache(
    const float* __restrict__ kc, const float* __restrict__ vc,
    float* __restrict__ kout, float* __restrict__ vout)
{
    size_t i4 = (size_t)blockIdx.x * 256 + threadIdx.x;   // float4 units
    const float* src = blockIdx.y ? vc : kc;
    float* dst = blockIdx.y ? vout : kout;
    size_t e = i4 * 4;                 // element in [B,H,1024,128]
    size_t bh = e >> 17;
    size_t rem = e & 131071;
    f32x4 v = *(const f32x4*)(src + e);
    *(f32x4*)(dst + (bh << 18) + rem) = v;   // [B,H,2048,128], rows 0..1023
}

// ---------------- k_cache -> Kbf bf16 rows 0..1023 ----------------
__global__ __launch_bounds__(256) void conv_cache_k(
    const float* __restrict__ kc, unsigned short* __restrict__ Kbf)
{
    size_t i4 = (size_t)blockIdx.x * 256 + threadIdx.x;   // 2,097,152 total
    size_t e = i4 * 4;
    size_t bh = e >> 17;
    size_t rem = e & 131071;
    f32x4 v = *(const f32x4*)(kc + e);
    ushort4 pk = { f2bf(v[0]), f2bf(v[1]), f2bf(v[2]), f2bf(v[3]) };
    *(ushort4*)(Kbf + (bh << 18) + rem) = pk;
}

// ---------------- v_cache -> Vtb bf16 transposed [B,H,128,2048] cols 0..1023 ----------------
__global__ __launch_bounds__(256) void conv_cache_vt(
    const float* __restrict__ vc, unsigned short* __restrict__ Vtb)
{
    __shared__ unsigned short T[128 * 72];
    const int kv0 = blockIdx.x * 64;
    const int bh = blockIdx.y;
    const int tid = threadIdx.x;
    const float* src = vc + ((size_t)bh << 17) + (size_t)kv0 * 128;
    #pragma unroll
    for (int r = 0; r < 8; ++r) {
        int e4 = r * 256 + tid;
        int kv = e4 >> 5, d0 = (e4 & 31) << 2;
        f32x4 v = *(const f32x4*)(src + kv * 128 + d0);
        #pragma unroll
        for (int i = 0; i < 4; ++i) T[(d0 + i) * 72 + kv] = f2bf(v[i]);
    }
    __syncthreads();
    #pragma unroll
    for (int r = 0; r < 8; ++r) {
        int e = r * 256 + tid;
        int d = e >> 4, k4 = (e & 15) << 2;
        ushort4 pk = { T[d * 72 + k4], T[d * 72 + k4 + 1], T[d * 72 + k4 + 2], T[d * 72 + k4 + 3] };
        *(ushort4*)(Vtb + ((size_t)bh * 128 + d) * 2048 + kv0 + k4) = pk;
    }
}

// ---------------- fp32 -> bf16 convert ----------------
__global__ __launch_bounds__(256) void f32_to_bf16(
    const float* __restrict__ src, unsigned short* __restrict__ dst, int n4)
{
    int i = blockIdx.x * 256 + threadIdx.x;
    if (i >= n4) return;
    f32x4 v = *(const f32x4*)(src + (size_t)i * 4);
    ushort4 pk = { f2bf(v[0]), f2bf(v[1]), f2bf(v[2]), f2bf(v[3]) };
    *(ushort4*)(dst + (size_t)i * 4) = pk;
}

// ---------------- GEMM: Y[m,n] = sum_k A[m,k]*W[n,k] + bias[n] ----------------
// MODE 0: bf16 -> ws Q [B,H,S,D], pre-scaled by QSCALE
// MODE 1: fp32 -> KV region rows 1024+, plus (dst2) bf16 Kbf rows 1024+
// MODE 3: fp32 -> KV region rows 1024+, plus (dst2) bf16 Vtb transposed cols 1024+
// MODE 2: fp32 row-major [m,n]
template<int MODE, bool ABF16, bool BBF16>
__global__ __launch_bounds__(256) void gemm_bt(
    const void* __restrict__ Ag, const void* __restrict__ Wg,
    const float* __restrict__ bias, void* __restrict__ dst, void* __restrict__ dst2)
{
    const int tid = threadIdx.x;
    const int lane = tid & 63;
    const int w = tid >> 6;
    const int g = lane >> 4;
    const int c = lane & 15;
    const int wr = w >> 1, wc = w & 1;
    const int m0 = blockIdx.y * 128;
    const int n0 = blockIdx.x * 128;

    __shared__ unsigned short As[128 * 40];
    __shared__ unsigned short Bs[128 * 40];

    f32x4 acc[4][4];
    #pragma unroll
    for (int i = 0; i < 4; ++i)
        #pragma unroll
        for (int j = 0; j < 4; ++j)
            acc[i][j] = f32x4{0.f, 0.f, 0.f, 0.f};

    for (int k0 = 0; k0 < DIMK; k0 += 32) {
        __syncthreads();
        if constexpr (ABF16) {
            const unsigned short* A16 = (const unsigned short*)Ag;
            #pragma unroll
            for (int r = 0; r < 2; ++r) {
                int e8 = r * 256 + tid;
                int row = e8 >> 2, col = (e8 & 3) << 3;
                *(uint4*)(&As[row * 40 + col]) =
                    *(const uint4*)(A16 + (size_t)(m0 + row) * DIMK + k0 + col);
            }
        } else {
            const float* Af = (const float*)Ag;
            #pragma unroll
            for (int r = 0; r < 4; ++r) {
                int e4 = r * 256 + tid;
                int row = e4 >> 3, col = (e4 & 7) << 2;
                f32x4 v = *(const f32x4*)(Af + (size_t)(m0 + row) * DIMK + k0 + col);
                ushort4 pk = { f2bf(v[0]), f2bf(v[1]), f2bf(v[2]), f2bf(v[3]) };
                *(ushort4*)(&As[row * 40 + col]) = pk;
            }
        }
        if constexpr (BBF16) {
            const unsigned short* W16 = (const unsigned short*)Wg;
            #pragma unroll
            for (int r = 0; r < 2; ++r) {
                int e8 = r * 256 + tid;
                int row = e8 >> 2, col = (e8 & 3) << 3;
                *(uint4*)(&Bs[row * 40 + col]) =
                    *(const uint4*)(W16 + (size_t)(n0 + row) * DIMK + k0 + col);
            }
        } else {
            const float* Wf = (const float*)Wg;
            #pragma unroll
            for (int r = 0; r < 4; ++r) {
                int e4 = r * 256 + tid;
                int row = e4 >> 3, col = (e4 & 7) << 2;
                f32x4 v = *(const f32x4*)(Wf + (size_t)(n0 + row) * DIMK + k0 + col);
                ushort4 pk = { f2bf(v[0]), f2bf(v[1]), f2bf(v[2]), f2bf(v[3]) };
                *(ushort4*)(&Bs[row * 40 + col]) = pk;
            }
        }
        __syncthreads();

        bf16x8 af[4], bfr[4];
        #pragma unroll
        for (int i = 0; i < 4; ++i)
            af[i] = *(const bf16x8*)(&As[(wr * 64 + i * 16 + c) * 40 + g * 8]);
        #pragma unroll
        for (int i = 0; i < 4; ++i)
            bfr[i] = *(const bf16x8*)(&Bs[(wc * 64 + i * 16 + c) * 40 + g * 8]);
        #pragma unroll
        for (int i = 0; i < 4; ++i)
            #pragma unroll
            for (int j = 0; j < 4; ++j)
                acc[i][j] = __builtin_amdgcn_mfma_f32_16x16x32_bf16(af[i], bfr[j], acc[i][j], 0, 0, 0);
    }

    // ---- epilogue: C/D layout col=lane&15, row=(lane>>4)*4+reg ----
    #pragma unroll
    for (int j = 0; j < 4; ++j) {
        const int n = n0 + wc * 64 + j * 16 + c;
        const float bn = bias[n];
        #pragma unroll
        for (int i = 0; i < 4; ++i) {
            float y4[4];
            #pragma unroll
            for (int tq = 0; tq < 4; ++tq) y4[tq] = acc[i][j][tq] + bn;
            const int mb = m0 + wr * 64 + i * 16 + g * 4;
            if constexpr (MODE == 0) {
                #pragma unroll
                for (int tq = 0; tq < 4; ++tq) {
                    int m = mb + tq; int b = m >> 10, s = m & 1023;
                    int hh = n >> 7, d = n & 127;
                    ((unsigned short*)dst)[((((size_t)b * 16 + hh) << 10) + s) * 128 + d] = f2bf(y4[tq] * QSCALE);
                }
            } else if constexpr (MODE == 1) {
                #pragma unroll
                for (int tq = 0; tq < 4; ++tq) {
                    int m = mb + tq; int b = m >> 10, s = m & 1023;
                    int hh = n >> 7, d = n & 127;
                    ((float*)dst)[(((size_t)b * 16 + hh) * 2048 + 1024 + s) * 128 + d] = y4[tq];
                    if (dst2)
                        ((unsigned short*)dst2)[(((size_t)b * 16 + hh) << 18) + (size_t)(1024 + s) * 128 + d] = f2bf(y4[tq]);
                }
            } else if constexpr (MODE == 3) {
                #pragma unroll
                for (int tq = 0; tq < 4; ++tq) {
                    int m = mb + tq; int b = m >> 10, s = m & 1023;
                    int hh = n >> 7, d = n & 127;
                    ((float*)dst)[(((size_t)b * 16 + hh) * 2048 + 1024 + s) * 128 + d] = y4[tq];
                }
                if (dst2) {
                    int b = mb >> 10, s = mb & 1023;
                    int hh = n >> 7, d = n & 127;
                    ushort4 pk = { f2bf(y4[0]), f2bf(y4[1]), f2bf(y4[2]), f2bf(y4[3]) };
                    *(ushort4*)((unsigned short*)dst2 + (((size_t)b * 16 + hh) * 128 + d) * 2048 + 1024 + s) = pk;
                }
            } else {
                #pragma unroll
                for (int tq = 0; tq < 4; ++tq) {
                    int m = mb + tq;
                    ((float*)dst)[(size_t)m * 2048 + n] = y4[tq];
                }
            }
        }
    }
}

// ---------------- flash attention v2: direct-global bf16 K / Vt, no barriers ----------------
// grid (8 q-tiles, 64 bh), 4 waves x 32 q-rows, KVBLK=64. Q pre-scaled by QSCALE.
__global__ __launch_bounds__(256) void attn2(
    const unsigned short* __restrict__ Qbf,   // [B,H,1024,128] bf16, pre-scaled
    const unsigned short* __restrict__ Kbf,   // [B,H,2048,128] bf16
    const unsigned short* __restrict__ Vtb,   // [B,H,128,2048] bf16
    unsigned short* __restrict__ ctx)         // [B,S,dim] bf16
{
    const int qt = blockIdx.x;
    const int bh = blockIdx.y;
    const int b = bh >> 4, h = bh & 15;
    const int tid = threadIdx.x;
    const int lane = tid & 63;
    const int w = tid >> 6;
    const int g = lane >> 4;
    const int c = lane & 15;

    __shared__ unsigned short Ps[4 * 32 * 72];   // per-wave P [32][64], stride 72

    const unsigned short* Qb = Qbf + ((size_t)bh * 1024 + qt * 128) * 128;
    const unsigned short* Kb = Kbf + ((size_t)bh << 18);
    const unsigned short* Vt = Vtb + ((size_t)bh << 18);

    bf16x8 aq[2][4];
    #pragma unroll
    for (int m2 = 0; m2 < 2; ++m2)
        #pragma unroll
        for (int kk = 0; kk < 4; ++kk)
            aq[m2][kk] = *(const bf16x8*)(Qb + (w * 32 + m2 * 16 + c) * 128 + kk * 32 + g * 8);

    f32x4 od[2][8];
    #pragma unroll
    for (int m2 = 0; m2 < 2; ++m2)
        #pragma unroll
        for (int nf = 0; nf < 8; ++nf)
            od[m2][nf] = f32x4{0.f, 0.f, 0.f, 0.f};
    float mrow[2][4], lrow[2][4];
    #pragma unroll
    for (int m2 = 0; m2 < 2; ++m2)
        #pragma unroll
        for (int j = 0; j < 4; ++j) { mrow[m2][j] = -1e30f; lrow[m2][j] = 0.f; }

    const int ntiles = 18 + 2 * qt;
    const int lim_min = 1024 + qt * 128 + w * 32;   // min lim among this wave's rows
    unsigned short* Pw = &Ps[w * 32 * 72];

    for (int t = 0; t < ntiles; ++t) {
        const int kv0 = t * 64;

        // ---- QK^T: direct global K fragments ----
        f32x4 sc[2][4];
        #pragma unroll
        for (int m2 = 0; m2 < 2; ++m2)
            #pragma unroll
            for (int n = 0; n < 4; ++n)
                sc[m2][n] = f32x4{0.f, 0.f, 0.f, 0.f};
        #pragma unroll
        for (int kk = 0; kk < 4; ++kk) {
            bf16x8 bk[4];
            #pragma unroll
            for (int n = 0; n < 4; ++n)
                bk[n] = *(const bf16x8*)(Kb + (size_t)(kv0 + n * 16 + c) * 128 + kk * 32 + g * 8);
            #pragma unroll
            for (int m2 = 0; m2 < 2; ++m2)
                #pragma unroll
                for (int n = 0; n < 4; ++n)
                    sc[m2][n] = __builtin_amdgcn_mfma_f32_16x16x32_bf16(aq[m2][kk], bk[n], sc[m2][n], 0, 0, 0);
        }

        // ---- online softmax (exp2 domain; scores pre-scaled via Q) ----
        const bool need_mask = (kv0 + 63 > lim_min);
        #pragma unroll
        for (int m2 = 0; m2 < 2; ++m2) {
            #pragma unroll
            for (int j = 0; j < 4; ++j) {
                float rmax = -1e30f;
                if (need_mask) {
                    const int lim = 1024 + qt * 128 + w * 32 + m2 * 16 + g * 4 + j;
                    #pragma unroll
                    for (int n = 0; n < 4; ++n) {
                        float s = sc[m2][n][j];
                        if (kv0 + n * 16 + c > lim) s = -1e30f;
                        sc[m2][n][j] = s;
                        rmax = fmaxf(rmax, s);
                    }
                } else {
                    #pragma unroll
                    for (int n = 0; n < 4; ++n)
                        rmax = fmaxf(rmax, sc[m2][n][j]);
                }
                #pragma unroll
                for (int off = 1; off < 16; off <<= 1)
                    rmax = fmaxf(rmax, __shfl_xor(rmax, off));
                float mold = mrow[m2][j];
                float mnew = fmaxf(mold, rmax);
                mrow[m2][j] = mnew;
                float fs = exp2f(mold - mnew);
                float rsum = 0.f;
                #pragma unroll
                for (int n = 0; n < 4; ++n) {
                    float p = exp2f(sc[m2][n][j] - mnew);
                    sc[m2][n][j] = p;
                    rsum += p;
                }
                #pragma unroll
                for (int off = 1; off < 16; off <<= 1)
                    rsum += __shfl_xor(rsum, off);
                lrow[m2][j] = lrow[m2][j] * fs + rsum;
                #pragma unroll
                for (int nf = 0; nf < 8; ++nf)
                    od[m2][nf][j] *= fs;
            }
        }

        // ---- P -> LDS (bf16), wave-private, no barrier ----
        #pragma unroll
        for (int m2 = 0; m2 < 2; ++m2)
            #pragma unroll
            for (int n = 0; n < 4; ++n)
                #pragma unroll
                for (int j = 0; j < 4; ++j)
                    Pw[(m2 * 16 + g * 4 + j) * 72 + n * 16 + c] = f2bf(sc[m2][n][j]);

        // ---- PV: direct global Vt fragments ----
        #pragma unroll
        for (int kk = 0; kk < 2; ++kk) {
            bf16x8 ap0 = *(const bf16x8*)(&Pw[(c) * 72 + kk * 32 + g * 8]);
            bf16x8 ap1 = *(const bf16x8*)(&Pw[(16 + c) * 72 + kk * 32 + g * 8]);
            #pragma unroll
            for (int nf = 0; nf < 8; ++nf) {
                bf16x8 bv = *(const bf16x8*)(Vt + (size_t)(nf * 16 + c) * 2048 + kv0 + kk * 32 + g * 8);
                od[0][nf] = __builtin_amdgcn_mfma_f32_16x16x32_bf16(ap0, bv, od[0][nf], 0, 0, 0);
                od[1][nf] = __builtin_amdgcn_mfma_f32_16x16x32_bf16(ap1, bv, od[1][nf], 0, 0, 0);
            }
        }
    }

    // ---- epilogue ----
    #pragma unroll
    for (int m2 = 0; m2 < 2; ++m2) {
        #pragma unroll
        for (int j = 0; j < 4; ++j) {
            const int qg = qt * 128 + w * 32 + m2 * 16 + g * 4 + j;
            const float rl = 1.0f / lrow[m2][j];
            #pragma unroll
            for (int nf = 0; nf < 8; ++nf) {
                const int d = nf * 16 + c;
                ctx[((size_t)b * 1024 + qg) * 2048 + h * 128 + d] = f2bf(od[m2][nf][j] * rl);
            }
        }
    }
}

// ---------------- flash attention (round-1 fallback, fp32 K/V with staging) ----------------
__global__ __launch_bounds__(256) void attn_stage(
    const unsigned short* __restrict__ Qbf,
    const float* __restrict__ Kf, const float* __restrict__ Vf,
    unsigned short* __restrict__ ctx)
{
    const int qt = blockIdx.x;
    const int bh = blockIdx.y;
    const int b = bh >> 4, h = bh & 15;
    const int tid = threadIdx.x;
    const int lane = tid & 63;
    const int w = tid >> 6;
    const int g = lane >> 4;
    const int c = lane & 15;

    __shared__ unsigned short Ks[64 * 136];
    __shared__ unsigned short Vt[128 * 72];
    __shared__ unsigned short Ps[4 * 32 * 72];

    bf16x8 aq[2][4];
    const unsigned short* Qb = Qbf + ((size_t)bh * 1024 + qt * 128) * 128;
    #pragma unroll
    for (int m2 = 0; m2 < 2; ++m2)
        #pragma unroll
        for (int kk = 0; kk < 4; ++kk)
            aq[m2][kk] = *(const bf16x8*)(Qb + (w * 32 + m2 * 16 + c) * 128 + kk * 32 + g * 8);

    f32x4 od[2][8];
    #pragma unroll
    for (int m2 = 0; m2 < 2; ++m2)
        #pragma unroll
        for (int nf = 0; nf < 8; ++nf)
            od[m2][nf] = f32x4{0.f, 0.f, 0.f, 0.f};
    float mrow[2][4], lrow[2][4];
    #pragma unroll
    for (int m2 = 0; m2 < 2; ++m2)
        #pragma unroll
        for (int j = 0; j < 4; ++j) { mrow[m2][j] = -1e30f; lrow[m2][j] = 0.f; }

    const float* Kb = Kf + (size_t)bh * 2048 * 128;
    const float* Vb = Vf + (size_t)bh * 2048 * 128;
    const int ntiles = 18 + 2 * qt;

    for (int t = 0; t < ntiles; ++t) {
        __syncthreads();
        const float* Kt = Kb + (size_t)t * 64 * 128;
        #pragma unroll
        for (int r = 0; r < 8; ++r) {
            int e4 = r * 256 + tid;
            int kv = e4 >> 5, d0 = (e4 & 31) << 2;
            f32x4 v = *(const f32x4*)(Kt + kv * 128 + d0);
            ushort4 pk = { f2bf(v[0]), f2bf(v[1]), f2bf(v[2]), f2bf(v[3]) };
            *(ushort4*)(&Ks[kv * 136 + d0]) = pk;
        }
        const float* Vg = Vb + (size_t)t * 64 * 128;
        #pragma unroll
        for (int r = 0; r < 8; ++r) {
            int e4 = tid * 8 + r;
            int kv = e4 >> 5, d0 = (e4 & 31) << 2;
            f32x4 v = *(const f32x4*)(Vg + kv * 128 + d0);
            #pragma unroll
            for (int i = 0; i < 4; ++i)
                Vt[(d0 + i) * 72 + kv] = f2bf(v[i]);
        }
        __syncthreads();

        f32x4 sc[2][4];
        #pragma unroll
        for (int m2 = 0; m2 < 2; ++m2)
            #pragma unroll
            for (int n = 0; n < 4; ++n)
                sc[m2][n] = f32x4{0.f, 0.f, 0.f, 0.f};
        #pragma unroll
        for (int kk = 0; kk < 4; ++kk) {
            bf16x8 bk[4];
            #pragma unroll
            for (int n = 0; n < 4; ++n)
                bk[n] = *(const bf16x8*)(&Ks[(n * 16 + c) * 136 + kk * 32 + g * 8]);
            #pragma unroll
            for (int m2 = 0; m2 < 2; ++m2)
                #pragma unroll
                for (int n = 0; n < 4; ++n)
                    sc[m2][n] = __builtin_amdgcn_mfma_f32_16x16x32_bf16(aq[m2][kk], bk[n], sc[m2][n], 0, 0, 0);
        }

        const int kvbase = t * 64;
        #pragma unroll
        for (int m2 = 0; m2 < 2; ++m2) {
            #pragma unroll
            for (int j = 0; j < 4; ++j) {
                const int qg = qt * 128 + w * 32 + m2 * 16 + g * 4 + j;
                const int lim = qg + 1024;
                float rmax = -1e30f;
                #pragma unroll
                for (int n = 0; n < 4; ++n) {
                    float s = sc[m2][n][j];
                    if (kvbase + n * 16 + c > lim) s = -1e30f;
                    sc[m2][n][j] = s;
                    rmax = fmaxf(rmax, s);
                }
                #pragma unroll
                for (int off = 1; off < 16; off <<= 1)
                    rmax = fmaxf(rmax, __shfl_xor(rmax, off));
                float mold = mrow[m2][j];
                float mnew = fmaxf(mold, rmax);
                mrow[m2][j] = mnew;
                float fs = exp2f(mold - mnew);
                float rsum = 0.f;
                #pragma unroll
                for (int n = 0; n < 4; ++n) {
                    float p = exp2f(sc[m2][n][j] - mnew);
                    sc[m2][n][j] = p;
                    rsum += p;
                }
                #pragma unroll
                for (int off = 1; off < 16; off <<= 1)
                    rsum += __shfl_xor(rsum, off);
                lrow[m2][j] = lrow[m2][j] * fs + rsum;
                #pragma unroll
                for (int nf = 0; nf < 8; ++nf)
                    od[m2][nf][j] *= fs;
            }
        }

        unsigned short* Pw = &Ps[w * 32 * 72];
        #pragma unroll
        for (int m2 = 0; m2 < 2; ++m2)
            #pragma unroll
            for (int n = 0; n < 4; ++n)
                #pragma unroll
                for (int j = 0; j < 4; ++j)
                    Pw[(m2 * 16 + g * 4 + j) * 72 + n * 16 + c] = f2bf(sc[m2][n][j]);

        #pragma unroll
        for (int kk = 0; kk < 2; ++kk) {
            bf16x8 ap0 = *(const bf16x8*)(&Ps[(w * 32 + c) * 72 + kk * 32 + g * 8]);
            bf16x8 ap1 = *(const bf16x8*)(&Ps[(w * 32 + 16 + c) * 72 + kk * 32 + g * 8]);
            #pragma unroll
            for (int nf = 0; nf < 8; ++nf) {
                bf16x8 bv = *(const bf16x8*)(&Vt[(nf * 16 + c) * 72 + kk * 32 + g * 8]);
                od[0][nf] = __builtin_amdgcn_mfma_f32_16x16x32_bf16(ap0, bv, od[0][nf], 0, 0, 0);
                od[1][nf] = __builtin_amdgcn_mfma_f32_16x16x32_bf16(ap1, bv, od[1][nf], 0, 0, 0);
            }
        }
    }

    #pragma unroll
    for (int m2 = 0; m2 < 2; ++m2) {
        #pragma unroll
        for (int j = 0; j < 4; ++j) {
            const int qg = qt * 128 + w * 32 + m2 * 16 + g * 4 + j;
            const float rl = 1.0f / lrow[m2][j];
            #pragma unroll
            for (int nf = 0; nf < 8; ++nf) {
                const int d = nf * 16 + c;
                ctx[((size_t)b * 1024 + qg) * 2048 + h * 128 + d] = f2bf(od[m2][nf][j] * rl);
            }
        }
    }
}

extern "C" void kernel_launch(void* const* d_in, const int* in_sizes, int n_in,
                              void* d_out, int out_size, void* d_ws, size_t ws_size,
                              hipStream_t stream) {
    const float* x  = (const float*)d_in[0];
    const float* kc = (const float*)d_in[1];
    const float* vc = (const float*)d_in[2];
    const float* Wq = (const float*)d_in[3];
    const float* bq = (const float*)d_in[4];
    const float* Wk = (const float*)d_in[5];
    const float* bk = (const float*)d_in[6];
    const float* Wv = (const float*)d_in[7];
    const float* bv = (const float*)d_in[8];
    const float* Wo = (const float*)d_in[9];
    const float* bo = (const float*)d_in[10];

    float* outp = (float*)d_out;
    float* kout = outp + (size_t)8388608;   // k region [4,16,2048,128]
    float* vout = outp + (size_t)25165824;  // v region

    // ws layout (ushort units)
    unsigned short* Qbf = (unsigned short*)d_ws;          //  8,388,608
    unsigned short* ctx = Qbf + (size_t)8388608;          //  8,388,608
    unsigned short* Kbf = ctx + (size_t)8388608;          // 16,777,216
    unsigned short* Vtb = Kbf + (size_t)16777216;         // 16,777,216
    unsigned short* xbf = Vtb + (size_t)16777216;         //  8,388,608
    unsigned short* Wqb = xbf + (size_t)8388608;          //  4,194,304 each
    unsigned short* Wkb = Wqb + (size_t)4194304;
    unsigned short* Wvb = Wkb + (size_t)4194304;
    unsigned short* Wob = Wvb + (size_t)4194304;

    copy_cache<<<dim3(8192, 2), 256, 0, stream>>>(kc, vc, kout, vout);

    const bool full = ws_size >= (size_t)150994944;   // Qbf..Wob
    const bool mid  = ws_size >= (size_t)100663296;   // Qbf..Vtb

    if (full) {
        f32_to_bf16<<<8192, 256, 0, stream>>>(x,  xbf, 2097152);
        f32_to_bf16<<<4096, 256, 0, stream>>>(Wq, Wqb, 1048576);
        f32_to_bf16<<<4096, 256, 0, stream>>>(Wk, Wkb, 1048576);
        f32_to_bf16<<<4096, 256, 0, stream>>>(Wv, Wvb, 1048576);
        f32_to_bf16<<<4096, 256, 0, stream>>>(Wo, Wob, 1048576);
        conv_cache_k<<<8192, 256, 0, stream>>>(kc, Kbf);
        conv_cache_vt<<<dim3(16, 64), 256, 0, stream>>>(vc, Vtb);
        gemm_bt<0, true, true><<<dim3(16, 32), 256, 0, stream>>>(xbf, Wqb, bq, Qbf, nullptr);
        gemm_bt<1, true, true><<<dim3(16, 32), 256, 0, stream>>>(xbf, Wkb, bk, kout, Kbf);
        gemm_bt<3, true, true><<<dim3(16, 32), 256, 0, stream>>>(xbf, Wvb, bv, vout, Vtb);
        attn2<<<dim3(8, 64), 256, 0, stream>>>(Qbf, Kbf, Vtb, ctx);
        gemm_bt<2, true, true><<<dim3(16, 32), 256, 0, stream>>>(ctx, Wob, bo, outp, nullptr);
    } else if (mid) {
        conv_cache_k<<<8192, 256, 0, stream>>>(kc, Kbf);
        conv_cache_vt<<<dim3(16, 64), 256, 0, stream>>>(vc, Vtb);
        gemm_bt<0, false, false><<<dim3(16, 32), 256, 0, stream>>>(x, Wq, bq, Qbf, nullptr);
        gemm_bt<1, false, false><<<dim3(16, 32), 256, 0, stream>>>(x, Wk, bk, kout, Kbf);
        gemm_bt<3, false, false><<<dim3(16, 32), 256, 0, stream>>>(x, Wv, bv, vout, Vtb);
        attn2<<<dim3(8, 64), 256, 0, stream>>>(Qbf, Kbf, Vtb, ctx);
        gemm_bt<2, true, false><<<dim3(16, 32), 256, 0, stream>>>(ctx, Wo, bo, outp, nullptr);
    } else {
        gemm_bt<0, false, false><<<dim3(16, 32), 256, 0, stream>>>(x, Wq, bq, Qbf, nullptr);
        gemm_bt<1, false, false><<<dim3(16, 32), 256, 0, stream>>>(x, Wk, bk, kout, nullptr);
        gemm_bt<3, false, false><<<dim3(16, 32), 256, 0, stream>>>(x, Wv, bv, vout, nullptr);
        attn_stage<<<dim3(8, 64), 256, 0, stream>>>(Qbf, kout, vout, ctx);
        gemm_bt<2, true, false><<<dim3(16, 32), 256, 0, stream>>>(ctx, Wo, bo, outp, nullptr);
    }
}

// Round 3
// 609.637 us; speedup vs baseline: 1.2053x; 1.2053x over previous
//
#include <hip/hip_runtime.h>
#include <hip/hip_bf16.h>

typedef float f32x4 __attribute__((ext_vector_type(4)));
typedef __bf16 bf16x8 __attribute__((ext_vector_type(8)));

// ---- constants: B=4, S=1024, dim=2048, H=16, D=128, T=1024, KV=2048, M=4096
#define DIMK 2048
#define QSCALE ((float)(0.08838834764831845 * 1.4426950408889634))  // 1/sqrt(128)*log2(e)

__device__ __forceinline__ unsigned short f2bf(float f) {
    union { float f; unsigned int u; } v; v.f = f;
    unsigned int r = v.u + 0x7fffu + ((v.u >> 16) & 1u);
    return (unsigned short)(r >> 16);
}

// async global->LDS 16B copy. lds must be wave-uniform base; HW adds lane*16.
__device__ __forceinline__ void lds_load16(void* lds, const void* gsrc) {
    __builtin_amdgcn_global_load_lds(
        (const __attribute__((address_space(1))) unsigned int*)gsrc,
        (__attribute__((address_space(3))) unsigned int*)lds,
        16, 0, 0);
}

// ---------------- cache copy: k_cache/v_cache -> d_out k/v regions (fp32) ----------------
__global__ __launch_bounds__(256) void copy_cache(
    const float* __restrict__ kc, const float* __restrict__ vc,
    float* __restrict__ kout, float* __restrict__ vout)
{
    size_t i4 = (size_t)blockIdx.x * 256 + threadIdx.x;
    const float* src = blockIdx.y ? vc : kc;
    float* dst = blockIdx.y ? vout : kout;
    size_t e = i4 * 4;
    size_t bh = e >> 17;
    size_t rem = e & 131071;
    f32x4 v = *(const f32x4*)(src + e);
    *(f32x4*)(dst + (bh << 18) + rem) = v;
}

// ---------------- k_cache -> Kbf bf16 rows 0..1023 ----------------
__global__ __launch_bounds__(256) void conv_cache_k(
    const float* __restrict__ kc, unsigned short* __restrict__ Kbf)
{
    size_t i4 = (size_t)blockIdx.x * 256 + threadIdx.x;
    size_t e = i4 * 4;
    size_t bh = e >> 17;
    size_t rem = e & 131071;
    f32x4 v = *(const f32x4*)(kc + e);
    ushort4 pk = { f2bf(v[0]), f2bf(v[1]), f2bf(v[2]), f2bf(v[3]) };
    *(ushort4*)(Kbf + (bh << 18) + rem) = pk;
}

// ---------------- v_cache -> Vtb bf16 transposed [B,H,128,2048] cols 0..1023 ----------------
__global__ __launch_bounds__(256) void conv_cache_vt(
    const float* __restrict__ vc, unsigned short* __restrict__ Vtb)
{
    __shared__ unsigned short T[128 * 72];
    const int kv0 = blockIdx.x * 64;
    const int bh = blockIdx.y;
    const int tid = threadIdx.x;
    const float* src = vc + ((size_t)bh << 17) + (size_t)kv0 * 128;
    #pragma unroll
    for (int r = 0; r < 8; ++r) {
        int e4 = r * 256 + tid;
        int kv = e4 >> 5, d0 = (e4 & 31) << 2;
        f32x4 v = *(const f32x4*)(src + kv * 128 + d0);
        #pragma unroll
        for (int i = 0; i < 4; ++i) T[(d0 + i) * 72 + kv] = f2bf(v[i]);
    }
    __syncthreads();
    #pragma unroll
    for (int r = 0; r < 8; ++r) {
        int e = r * 256 + tid;
        int d = e >> 4, k4 = (e & 15) << 2;
        ushort4 pk = { T[d * 72 + k4], T[d * 72 + k4 + 1], T[d * 72 + k4 + 2], T[d * 72 + k4 + 3] };
        *(ushort4*)(Vtb + ((size_t)bh * 128 + d) * 2048 + kv0 + k4) = pk;
    }
}

// ---------------- fp32 -> bf16 convert ----------------
__global__ __launch_bounds__(256) void f32_to_bf16(
    const float* __restrict__ src, unsigned short* __restrict__ dst, int n4)
{
    int i = blockIdx.x * 256 + threadIdx.x;
    if (i >= n4) return;
    f32x4 v = *(const f32x4*)(src + (size_t)i * 4);
    ushort4 pk = { f2bf(v[0]), f2bf(v[1]), f2bf(v[2]), f2bf(v[3]) };
    *(ushort4*)(dst + (size_t)i * 4) = pk;
}

// ============ shared GEMM epilogue ============
// C/D layout col=lane&15, row=(lane>>4)*4+reg
template<int MODE>
__device__ __forceinline__ void gemm_epilogue(
    f32x4 (&acc)[4][4], const float* bias, void* dst, void* dst2,
    int m0, int n0, int wr, int wc, int g, int c)
{
    #pragma unroll
    for (int j = 0; j < 4; ++j) {
        const int n = n0 + wc * 64 + j * 16 + c;
        const float bn = bias[n];
        #pragma unroll
        for (int i = 0; i < 4; ++i) {
            float y4[4];
            #pragma unroll
            for (int tq = 0; tq < 4; ++tq) y4[tq] = acc[i][j][tq] + bn;
            const int mb = m0 + wr * 64 + i * 16 + g * 4;
            if constexpr (MODE == 0) {
                #pragma unroll
                for (int tq = 0; tq < 4; ++tq) {
                    int m = mb + tq; int b = m >> 10, s = m & 1023;
                    int hh = n >> 7, d = n & 127;
                    ((unsigned short*)dst)[((((size_t)b * 16 + hh) << 10) + s) * 128 + d] = f2bf(y4[tq] * QSCALE);
                }
            } else if constexpr (MODE == 1) {
                #pragma unroll
                for (int tq = 0; tq < 4; ++tq) {
                    int m = mb + tq; int b = m >> 10, s = m & 1023;
                    int hh = n >> 7, d = n & 127;
                    ((float*)dst)[(((size_t)b * 16 + hh) * 2048 + 1024 + s) * 128 + d] = y4[tq];
                    if (dst2)
                        ((unsigned short*)dst2)[(((size_t)b * 16 + hh) << 18) + (size_t)(1024 + s) * 128 + d] = f2bf(y4[tq]);
                }
            } else if constexpr (MODE == 3) {
                #pragma unroll
                for (int tq = 0; tq < 4; ++tq) {
                    int m = mb + tq; int b = m >> 10, s = m & 1023;
                    int hh = n >> 7, d = n & 127;
                    ((float*)dst)[(((size_t)b * 16 + hh) * 2048 + 1024 + s) * 128 + d] = y4[tq];
                }
                if (dst2) {
                    int b = mb >> 10, s = mb & 1023;
                    int hh = n >> 7, d = n & 127;
                    ushort4 pk = { f2bf(y4[0]), f2bf(y4[1]), f2bf(y4[2]), f2bf(y4[3]) };
                    *(ushort4*)((unsigned short*)dst2 + (((size_t)b * 16 + hh) * 128 + d) * 2048 + 1024 + s) = pk;
                }
            } else {
                #pragma unroll
                for (int tq = 0; tq < 4; ++tq) {
                    int m = mb + tq;
                    ((float*)dst)[(size_t)m * 2048 + n] = y4[tq];
                }
            }
        }
    }
}

// ---------------- GEMM v2: bf16 inputs, m97 structure (global_load_lds, linear LDS) -------
// Y[m,n] = sum_k A[m,k]*W[n,k] + bias[n]; 128x128 tile, BK=32, 4 waves 2x2.
template<int MODE>
__global__ __launch_bounds__(256) void gemm_bt2(
    const unsigned short* __restrict__ A16, const unsigned short* __restrict__ W16,
    const float* __restrict__ bias, void* __restrict__ dst, void* __restrict__ dst2)
{
    const int tid = threadIdx.x;
    const int lane = tid & 63;
    const int w = tid >> 6;
    const int g = lane >> 4;
    const int c = lane & 15;
    const int wr = w >> 1, wc = w & 1;
    const int m0 = blockIdx.y * 128;
    const int n0 = blockIdx.x * 128;

    __shared__ unsigned short As[128 * 32];   // linear, rows of 64B
    __shared__ unsigned short Bs[128 * 32];

    // staging address components (per thread, invariant over k0)
    const int arow = tid >> 2;                 // e8 = r*256+tid, r in {0,1}: row = e8>>2
    const int acol = (tid & 3) << 3;           // elements

    f32x4 acc[4][4];
    #pragma unroll
    for (int i = 0; i < 4; ++i)
        #pragma unroll
        for (int j = 0; j < 4; ++j)
            acc[i][j] = f32x4{0.f, 0.f, 0.f, 0.f};

    const unsigned short* Arow0 = A16 + (size_t)(m0 + arow) * DIMK + acol;
    const unsigned short* Arow1 = A16 + (size_t)(m0 + 64 + arow) * DIMK + acol;
    const unsigned short* Wrow0 = W16 + (size_t)(n0 + arow) * DIMK + acol;
    const unsigned short* Wrow1 = W16 + (size_t)(n0 + 64 + arow) * DIMK + acol;
    unsigned short* AsB0 = &As[(w * 64) * 8];
    unsigned short* AsB1 = &As[(256 + w * 64) * 8];
    unsigned short* BsB0 = &Bs[(w * 64) * 8];
    unsigned short* BsB1 = &Bs[(256 + w * 64) * 8];

    for (int k0 = 0; k0 < DIMK; k0 += 32) {
        __syncthreads();
        lds_load16(AsB0, Arow0 + k0);
        lds_load16(AsB1, Arow1 + k0);
        lds_load16(BsB0, Wrow0 + k0);
        lds_load16(BsB1, Wrow1 + k0);
        __syncthreads();

        bf16x8 af[4], bfr[4];
        #pragma unroll
        for (int i = 0; i < 4; ++i)
            af[i] = *(const bf16x8*)(&As[(wr * 64 + i * 16 + c) * 32 + g * 8]);
        #pragma unroll
        for (int i = 0; i < 4; ++i)
            bfr[i] = *(const bf16x8*)(&Bs[(wc * 64 + i * 16 + c) * 32 + g * 8]);
        #pragma unroll
        for (int i = 0; i < 4; ++i)
            #pragma unroll
            for (int j = 0; j < 4; ++j)
                acc[i][j] = __builtin_amdgcn_mfma_f32_16x16x32_bf16(af[i], bfr[j], acc[i][j], 0, 0, 0);
    }

    gemm_epilogue<MODE>(acc, bias, dst, dst2, m0, n0, wr, wc, g, c);
}

// ---------------- GEMM v1 (reg-staging, fp32-capable fallback) ----------------
template<int MODE, bool ABF16, bool BBF16>
__global__ __launch_bounds__(256) void gemm_bt(
    const void* __restrict__ Ag, const void* __restrict__ Wg,
    const float* __restrict__ bias, void* __restrict__ dst, void* __restrict__ dst2)
{
    const int tid = threadIdx.x;
    const int lane = tid & 63;
    const int w = tid >> 6;
    const int g = lane >> 4;
    const int c = lane & 15;
    const int wr = w >> 1, wc = w & 1;
    const int m0 = blockIdx.y * 128;
    const int n0 = blockIdx.x * 128;

    __shared__ unsigned short As[128 * 40];
    __shared__ unsigned short Bs[128 * 40];

    f32x4 acc[4][4];
    #pragma unroll
    for (int i = 0; i < 4; ++i)
        #pragma unroll
        for (int j = 0; j < 4; ++j)
            acc[i][j] = f32x4{0.f, 0.f, 0.f, 0.f};

    for (int k0 = 0; k0 < DIMK; k0 += 32) {
        __syncthreads();
        if constexpr (ABF16) {
            const unsigned short* A16 = (const unsigned short*)Ag;
            #pragma unroll
            for (int r = 0; r < 2; ++r) {
                int e8 = r * 256 + tid;
                int row = e8 >> 2, col = (e8 & 3) << 3;
                *(uint4*)(&As[row * 40 + col]) =
                    *(const uint4*)(A16 + (size_t)(m0 + row) * DIMK + k0 + col);
            }
        } else {
            const float* Af = (const float*)Ag;
            #pragma unroll
            for (int r = 0; r < 4; ++r) {
                int e4 = r * 256 + tid;
                int row = e4 >> 3, col = (e4 & 7) << 2;
                f32x4 v = *(const f32x4*)(Af + (size_t)(m0 + row) * DIMK + k0 + col);
                ushort4 pk = { f2bf(v[0]), f2bf(v[1]), f2bf(v[2]), f2bf(v[3]) };
                *(ushort4*)(&As[row * 40 + col]) = pk;
            }
        }
        if constexpr (BBF16) {
            const unsigned short* W16 = (const unsigned short*)Wg;
            #pragma unroll
            for (int r = 0; r < 2; ++r) {
                int e8 = r * 256 + tid;
                int row = e8 >> 2, col = (e8 & 3) << 3;
                *(uint4*)(&Bs[row * 40 + col]) =
                    *(const uint4*)(W16 + (size_t)(n0 + row) * DIMK + k0 + col);
            }
        } else {
            const float* Wf = (const float*)Wg;
            #pragma unroll
            for (int r = 0; r < 4; ++r) {
                int e4 = r * 256 + tid;
                int row = e4 >> 3, col = (e4 & 7) << 2;
                f32x4 v = *(const f32x4*)(Wf + (size_t)(m0 + row) * DIMK + k0 + col);
                ushort4 pk = { f2bf(v[0]), f2bf(v[1]), f2bf(v[2]), f2bf(v[3]) };
                *(ushort4*)(&Bs[row * 40 + col]) = pk;
            }
        }
        __syncthreads();

        bf16x8 af[4], bfr[4];
        #pragma unroll
        for (int i = 0; i < 4; ++i)
            af[i] = *(const bf16x8*)(&As[(wr * 64 + i * 16 + c) * 40 + g * 8]);
        #pragma unroll
        for (int i = 0; i < 4; ++i)
            bfr[i] = *(const bf16x8*)(&Bs[(wc * 64 + i * 16 + c) * 40 + g * 8]);
        #pragma unroll
        for (int i = 0; i < 4; ++i)
            #pragma unroll
            for (int j = 0; j < 4; ++j)
                acc[i][j] = __builtin_amdgcn_mfma_f32_16x16x32_bf16(af[i], bfr[j], acc[i][j], 0, 0, 0);
    }

    gemm_epilogue<MODE>(acc, bias, dst, dst2, m0, n0, wr, wc, g, c);
}

// ---------------- flash attention v3: LDS-staged bf16 K/Vt via global_load_lds,
//                  XOR-swizzled via pre-swizzled global source ----------------
// grid (8 q-tiles, 64 bh), 4 waves x 32 q-rows, KVBLK=64. Q pre-scaled by QSCALE.
__global__ __launch_bounds__(256) void attn3(
    const unsigned short* __restrict__ Qbf,   // [B,H,1024,128] bf16, pre-scaled
    const unsigned short* __restrict__ Kbf,   // [B,H,2048,128] bf16
    const unsigned short* __restrict__ Vtb,   // [B,H,128,2048] bf16
    unsigned short* __restrict__ ctx)         // [B,S,dim] bf16
{
    const int qt = blockIdx.x;
    const int bh = blockIdx.y;
    const int b = bh >> 4, h = bh & 15;
    const int tid = threadIdx.x;
    const int lane = tid & 63;
    const int w = tid >> 6;
    const int g = lane >> 4;
    const int c = lane & 15;

    __shared__ unsigned short Ks[64 * 128];   // [kv][d] bf16, XOR-swizzled rows (256B)
    __shared__ unsigned short Vs[128 * 64];   // [d][kv] bf16, XOR-swizzled rows (128B)
    __shared__ unsigned short Ps[4 * 32 * 72];

    const unsigned short* Qb = Qbf + ((size_t)bh * 1024 + qt * 128) * 128;
    const unsigned short* Kb = Kbf + ((size_t)bh << 18);
    const unsigned short* Vt = Vtb + ((size_t)bh << 18);

    bf16x8 aq[2][4];
    #pragma unroll
    for (int m2 = 0; m2 < 2; ++m2)
        #pragma unroll
        for (int kk = 0; kk < 4; ++kk)
            aq[m2][kk] = *(const bf16x8*)(Qb + (w * 32 + m2 * 16 + c) * 128 + kk * 32 + g * 8);

    f32x4 od[2][8];
    #pragma unroll
    for (int m2 = 0; m2 < 2; ++m2)
        #pragma unroll
        for (int nf = 0; nf < 8; ++nf)
            od[m2][nf] = f32x4{0.f, 0.f, 0.f, 0.f};
    float mrow[2][4], lrow[2][4];
    #pragma unroll
    for (int m2 = 0; m2 < 2; ++m2)
        #pragma unroll
        for (int j = 0; j < 4; ++j) { mrow[m2][j] = -1e30f; lrow[m2][j] = 0.f; }

    // per-thread staging constants (4 issues of 256 lanes each, 16B/lane)
    // K tile [64][128]: LDS byte p=e8*16 -> row=e8>>4, colbyte=(e8&15)<<4 ; swizzled source
    const int krow = tid >> 4;                          // +16 per issue
    const int kswz = (((tid & 15) << 4) ^ ((krow & 7) << 4)) >> 1;  // krow&7 invariant: +16/issue
    // V tile [128][64]: row=e8>>3, colbyte=(e8&7)<<4
    const int vrow = tid >> 3;                          // +32 per issue
    const int vcolb = (tid & 7) << 4;
    const unsigned short* Kl = Kb + (size_t)krow * 128 + kswz;
    unsigned short* KsB = &Ks[(w * 64) * 8];
    unsigned short* VsB = &Vs[(w * 64) * 8];

    const int ntiles = 18 + 2 * qt;
    const int lim_min = 1024 + qt * 128 + w * 32;
    unsigned short* Pw = &Ps[w * 32 * 72];

    for (int t = 0; t < ntiles; ++t) {
        const int kv0 = t * 64;
        __syncthreads();   // previous tile's LDS reads complete
        // ---- stage K (4 x 4KB) and Vt (4 x 4KB), swizzled-source, linear LDS ----
        #pragma unroll
        for (int r = 0; r < 4; ++r)
            lds_load16(KsB + r * 2048, Kl + (size_t)(kv0 + r * 16) * 128);
        #pragma unroll
        for (int r = 0; r < 4; ++r) {
            int row = vrow + r * 32;
            int swz = (vcolb ^ ((row & 7) << 4)) >> 1;
            lds_load16(VsB + r * 2048, Vt + (size_t)row * 2048 + kv0 + swz);
        }
        __syncthreads();   // drains vmcnt -> tiles ready

        // ---- QK^T from LDS (swizzled reads) ----
        f32x4 sc[2][4];
        #pragma unroll
        for (int m2 = 0; m2 < 2; ++m2)
            #pragma unroll
            for (int n = 0; n < 4; ++n)
                sc[m2][n] = f32x4{0.f, 0.f, 0.f, 0.f};
        #pragma unroll
        for (int kk = 0; kk < 4; ++kk) {
            const int koff = ((kk * 64 + g * 16) ^ ((c & 7) << 4)) >> 1;
            bf16x8 bk[4];
            #pragma unroll
            for (int n = 0; n < 4; ++n)
                bk[n] = *(const bf16x8*)(&Ks[(n * 16 + c) * 128 + koff]);
            #pragma unroll
            for (int m2 = 0; m2 < 2; ++m2)
                #pragma unroll
                for (int n = 0; n < 4; ++n)
                    sc[m2][n] = __builtin_amdgcn_mfma_f32_16x16x32_bf16(aq[m2][kk], bk[n], sc[m2][n], 0, 0, 0);
        }

        // ---- online softmax (exp2 domain; scores pre-scaled via Q) ----
        const bool need_mask = (kv0 + 63 > lim_min);
        #pragma unroll
        for (int m2 = 0; m2 < 2; ++m2) {
            #pragma unroll
            for (int j = 0; j < 4; ++j) {
                float rmax = -1e30f;
                if (need_mask) {
                    const int lim = lim_min + m2 * 16 + g * 4 + j;
                    #pragma unroll
                    for (int n = 0; n < 4; ++n) {
                        float s = sc[m2][n][j];
                        if (kv0 + n * 16 + c > lim) s = -1e30f;
                        sc[m2][n][j] = s;
                        rmax = fmaxf(rmax, s);
                    }
                } else {
                    #pragma unroll
                    for (int n = 0; n < 4; ++n)
                        rmax = fmaxf(rmax, sc[m2][n][j]);
                }
                #pragma unroll
                for (int off = 1; off < 16; off <<= 1)
                    rmax = fmaxf(rmax, __shfl_xor(rmax, off));
                float mold = mrow[m2][j];
                float mnew = fmaxf(mold, rmax);
                mrow[m2][j] = mnew;
                float fs = exp2f(mold - mnew);
                float rsum = 0.f;
                #pragma unroll
                for (int n = 0; n < 4; ++n) {
                    float p = exp2f(sc[m2][n][j] - mnew);
                    sc[m2][n][j] = p;
                    rsum += p;
                }
                #pragma unroll
                for (int off = 1; off < 16; off <<= 1)
                    rsum += __shfl_xor(rsum, off);
                lrow[m2][j] = lrow[m2][j] * fs + rsum;
                #pragma unroll
                for (int nf = 0; nf < 8; ++nf)
                    od[m2][nf][j] *= fs;
            }
        }

        // ---- P -> LDS (bf16), wave-private, no barrier ----
        #pragma unroll
        for (int m2 = 0; m2 < 2; ++m2)
            #pragma unroll
            for (int n = 0; n < 4; ++n)
                #pragma unroll
                for (int j = 0; j < 4; ++j)
                    Pw[(m2 * 16 + g * 4 + j) * 72 + n * 16 + c] = f2bf(sc[m2][n][j]);

        // ---- PV from LDS Vs (swizzled reads) ----
        #pragma unroll
        for (int kk = 0; kk < 2; ++kk) {
            const int voff = ((kk * 64 + g * 16) ^ ((c & 7) << 4)) >> 1;
            bf16x8 ap0 = *(const bf16x8*)(&Pw[c * 72 + kk * 32 + g * 8]);
            bf16x8 ap1 = *(const bf16x8*)(&Pw[(16 + c) * 72 + kk * 32 + g * 8]);
            #pragma unroll
            for (int nf = 0; nf < 8; ++nf) {
                bf16x8 bv = *(const bf16x8*)(&Vs[(nf * 16 + c) * 64 + voff]);
                od[0][nf] = __builtin_amdgcn_mfma_f32_16x16x32_bf16(ap0, bv, od[0][nf], 0, 0, 0);
                od[1][nf] = __builtin_amdgcn_mfma_f32_16x16x32_bf16(ap1, bv, od[1][nf], 0, 0, 0);
            }
        }
    }

    // ---- epilogue ----
    #pragma unroll
    for (int m2 = 0; m2 < 2; ++m2) {
        #pragma unroll
        for (int j = 0; j < 4; ++j) {
            const int qg = qt * 128 + w * 32 + m2 * 16 + g * 4 + j;
            const float rl = 1.0f / lrow[m2][j];
            #pragma unroll
            for (int nf = 0; nf < 8; ++nf) {
                const int d = nf * 16 + c;
                ctx[((size_t)b * 1024 + qg) * 2048 + h * 128 + d] = f2bf(od[m2][nf][j] * rl);
            }
        }
    }
}

// ---------------- flash attention (small-ws fallback, fp32 K/V with staging) ----------------
__global__ __launch_bounds__(256) void attn_stage(
    const unsigned short* __restrict__ Qbf,
    const float* __restrict__ Kf, const float* __restrict__ Vf,
    unsigned short* __restrict__ ctx)
{
    const int qt = blockIdx.x;
    const int bh = blockIdx.y;
    const int b = bh >> 4, h = bh & 15;
    const int tid = threadIdx.x;
    const int lane = tid & 63;
    const int w = tid >> 6;
    const int g = lane >> 4;
    const int c = lane & 15;

    __shared__ unsigned short Ksl[64 * 136];
    __shared__ unsigned short Vtl[128 * 72];
    __shared__ unsigned short Ps[4 * 32 * 72];

    bf16x8 aq[2][4];
    const unsigned short* Qb = Qbf + ((size_t)bh * 1024 + qt * 128) * 128;
    #pragma unroll
    for (int m2 = 0; m2 < 2; ++m2)
        #pragma unroll
        for (int kk = 0; kk < 4; ++kk)
            aq[m2][kk] = *(const bf16x8*)(Qb + (w * 32 + m2 * 16 + c) * 128 + kk * 32 + g * 8);

    f32x4 od[2][8];
    #pragma unroll
    for (int m2 = 0; m2 < 2; ++m2)
        #pragma unroll
        for (int nf = 0; nf < 8; ++nf)
            od[m2][nf] = f32x4{0.f, 0.f, 0.f, 0.f};
    float mrow[2][4], lrow[2][4];
    #pragma unroll
    for (int m2 = 0; m2 < 2; ++m2)
        #pragma unroll
        for (int j = 0; j < 4; ++j) { mrow[m2][j] = -1e30f; lrow[m2][j] = 0.f; }

    const float* Kb = Kf + (size_t)bh * 2048 * 128;
    const float* Vb = Vf + (size_t)bh * 2048 * 128;
    const int ntiles = 18 + 2 * qt;
    const float scale2 = QSCALE;

    for (int t = 0; t < ntiles; ++t) {
        __syncthreads();
        const float* Kt = Kb + (size_t)t * 64 * 128;
        #pragma unroll
        for (int r = 0; r < 8; ++r) {
            int e4 = r * 256 + tid;
            int kv = e4 >> 5, d0 = (e4 & 31) << 2;
            f32x4 v = *(const f32x4*)(Kt + kv * 128 + d0);
            ushort4 pk = { f2bf(v[0]), f2bf(v[1]), f2bf(v[2]), f2bf(v[3]) };
            *(ushort4*)(&Ksl[kv * 136 + d0]) = pk;
        }
        const float* Vg = Vb + (size_t)t * 64 * 128;
        #pragma unroll
        for (int r = 0; r < 8; ++r) {
            int e4 = tid * 8 + r;
            int kv = e4 >> 5, d0 = (e4 & 31) << 2;
            f32x4 v = *(const f32x4*)(Vg + kv * 128 + d0);
            #pragma unroll
            for (int i = 0; i < 4; ++i)
                Vtl[(d0 + i) * 72 + kv] = f2bf(v[i]);
        }
        __syncthreads();

        f32x4 sc[2][4];
        #pragma unroll
        for (int m2 = 0; m2 < 2; ++m2)
            #pragma unroll
            for (int n = 0; n < 4; ++n)
                sc[m2][n] = f32x4{0.f, 0.f, 0.f, 0.f};
        #pragma unroll
        for (int kk = 0; kk < 4; ++kk) {
            bf16x8 bk[4];
            #pragma unroll
            for (int n = 0; n < 4; ++n)
                bk[n] = *(const bf16x8*)(&Ksl[(n * 16 + c) * 136 + kk * 32 + g * 8]);
            #pragma unroll
            for (int m2 = 0; m2 < 2; ++m2)
                #pragma unroll
                for (int n = 0; n < 4; ++n)
                    sc[m2][n] = __builtin_amdgcn_mfma_f32_16x16x32_bf16(aq[m2][kk], bk[n], sc[m2][n], 0, 0, 0);
        }

        const int kvbase = t * 64;
        #pragma unroll
        for (int m2 = 0; m2 < 2; ++m2) {
            #pragma unroll
            for (int j = 0; j < 4; ++j) {
                const int qg = qt * 128 + w * 32 + m2 * 16 + g * 4 + j;
                const int lim = qg + 1024;
                float rmax = -1e30f;
                #pragma unroll
                for (int n = 0; n < 4; ++n) {
                    float s = sc[m2][n][j] * scale2;
                    if (kvbase + n * 16 + c > lim) s = -1e30f;
                    sc[m2][n][j] = s;
                    rmax = fmaxf(rmax, s);
                }
                #pragma unroll
                for (int off = 1; off < 16; off <<= 1)
                    rmax = fmaxf(rmax, __shfl_xor(rmax, off));
                float mold = mrow[m2][j];
                float mnew = fmaxf(mold, rmax);
                mrow[m2][j] = mnew;
                float fs = exp2f(mold - mnew);
                float rsum = 0.f;
                #pragma unroll
                for (int n = 0; n < 4; ++n) {
                    float p = exp2f(sc[m2][n][j] - mnew);
                    sc[m2][n][j] = p;
                    rsum += p;
                }
                #pragma unroll
                for (int off = 1; off < 16; off <<= 1)
                    rsum += __shfl_xor(rsum, off);
                lrow[m2][j] = lrow[m2][j] * fs + rsum;
                #pragma unroll
                for (int nf = 0; nf < 8; ++nf)
                    od[m2][nf][j] *= fs;
            }
        }

        unsigned short* Pw = &Ps[w * 32 * 72];
        #pragma unroll
        for (int m2 = 0; m2 < 2; ++m2)
            #pragma unroll
            for (int n = 0; n < 4; ++n)
                #pragma unroll
                for (int j = 0; j < 4; ++j)
                    Pw[(m2 * 16 + g * 4 + j) * 72 + n * 16 + c] = f2bf(sc[m2][n][j]);

        #pragma unroll
        for (int kk = 0; kk < 2; ++kk) {
            bf16x8 ap0 = *(const bf16x8*)(&Ps[(w * 32 + c) * 72 + kk * 32 + g * 8]);
            bf16x8 ap1 = *(const bf16x8*)(&Ps[(w * 32 + 16 + c) * 72 + kk * 32 + g * 8]);
            #pragma unroll
            for (int nf = 0; nf < 8; ++nf) {
                bf16x8 bv = *(const bf16x8*)(&Vtl[(nf * 16 + c) * 72 + kk * 32 + g * 8]);
                od[0][nf] = __builtin_amdgcn_mfma_f32_16x16x32_bf16(ap0, bv, od[0][nf], 0, 0, 0);
                od[1][nf] = __builtin_amdgcn_mfma_f32_16x16x32_bf16(ap1, bv, od[1][nf], 0, 0, 0);
            }
        }
    }

    #pragma unroll
    for (int m2 = 0; m2 < 2; ++m2) {
        #pragma unroll
        for (int j = 0; j < 4; ++j) {
            const int qg = qt * 128 + w * 32 + m2 * 16 + g * 4 + j;
            const float rl = 1.0f / lrow[m2][j];
            #pragma unroll
            for (int nf = 0; nf < 8; ++nf) {
                const int d = nf * 16 + c;
                ctx[((size_t)b * 1024 + qg) * 2048 + h * 128 + d] = f2bf(od[m2][nf][j] * rl);
            }
        }
    }
}

extern "C" void kernel_launch(void* const* d_in, const int* in_sizes, int n_in,
                              void* d_out, int out_size, void* d_ws, size_t ws_size,
                              hipStream_t stream) {
    const float* x  = (const float*)d_in[0];
    const float* kc = (const float*)d_in[1];
    const float* vc = (const float*)d_in[2];
    const float* Wq = (const float*)d_in[3];
    const float* bq = (const float*)d_in[4];
    const float* Wk = (const float*)d_in[5];
    const float* bk = (const float*)d_in[6];
    const float* Wv = (const float*)d_in[7];
    const float* bv = (const float*)d_in[8];
    const float* Wo = (const float*)d_in[9];
    const float* bo = (const float*)d_in[10];

    float* outp = (float*)d_out;
    float* kout = outp + (size_t)8388608;   // k region [4,16,2048,128]
    float* vout = outp + (size_t)25165824;  // v region

    // ws layout (ushort units)
    unsigned short* Qbf = (unsigned short*)d_ws;          //  8,388,608
    unsigned short* ctx = Qbf + (size_t)8388608;          //  8,388,608
    unsigned short* Kbf = ctx + (size_t)8388608;          // 16,777,216
    unsigned short* Vtb = Kbf + (size_t)16777216;         // 16,777,216
    unsigned short* xbf = Vtb + (size_t)16777216;         //  8,388,608
    unsigned short* Wqb = xbf + (size_t)8388608;          //  4,194,304 each
    unsigned short* Wkb = Wqb + (size_t)4194304;
    unsigned short* Wvb = Wkb + (size_t)4194304;
    unsigned short* Wob = Wvb + (size_t)4194304;

    copy_cache<<<dim3(8192, 2), 256, 0, stream>>>(kc, vc, kout, vout);

    const bool full = ws_size >= (size_t)150994944;   // Qbf..Wob
    const bool mid  = ws_size >= (size_t)100663296;   // Qbf..Vtb

    if (full) {
        f32_to_bf16<<<8192, 256, 0, stream>>>(x,  xbf, 2097152);
        f32_to_bf16<<<4096, 256, 0, stream>>>(Wq, Wqb, 1048576);
        f32_to_bf16<<<4096, 256, 0, stream>>>(Wk, Wkb, 1048576);
        f32_to_bf16<<<4096, 256, 0, stream>>>(Wv, Wvb, 1048576);
        f32_to_bf16<<<4096, 256, 0, stream>>>(Wo, Wob, 1048576);
        conv_cache_k<<<8192, 256, 0, stream>>>(kc, Kbf);
        conv_cache_vt<<<dim3(16, 64), 256, 0, stream>>>(vc, Vtb);
        gemm_bt2<0><<<dim3(16, 32), 256, 0, stream>>>(xbf, Wqb, bq, Qbf, nullptr);
        gemm_bt2<1><<<dim3(16, 32), 256, 0, stream>>>(xbf, Wkb, bk, kout, Kbf);
        gemm_bt2<3><<<dim3(16, 32), 256, 0, stream>>>(xbf, Wvb, bv, vout, Vtb);
        attn3<<<dim3(8, 64), 256, 0, stream>>>(Qbf, Kbf, Vtb, ctx);
        gemm_bt2<2><<<dim3(16, 32), 256, 0, stream>>>(ctx, Wob, bo, outp, nullptr);
    } else if (mid) {
        conv_cache_k<<<8192, 256, 0, stream>>>(kc, Kbf);
        conv_cache_vt<<<dim3(16, 64), 256, 0, stream>>>(vc, Vtb);
        gemm_bt<0, false, false><<<dim3(16, 32), 256, 0, stream>>>(x, Wq, bq, Qbf, nullptr);
        gemm_bt<1, false, false><<<dim3(16, 32), 256, 0, stream>>>(x, Wk, bk, kout, Kbf);
        gemm_bt<3, false, false><<<dim3(16, 32), 256, 0, stream>>>(x, Wv, bv, vout, Vtb);
        attn3<<<dim3(8, 64), 256, 0, stream>>>(Qbf, Kbf, Vtb, ctx);
        gemm_bt<2, true, false><<<dim3(16, 32), 256, 0, stream>>>(ctx, Wo, bo, outp, nullptr);
    } else {
        gemm_bt<0, false, false><<<dim3(16, 32), 256, 0, stream>>>(x, Wq, bq, Qbf, nullptr);
        gemm_bt<1, false, false><<<dim3(16, 32), 256, 0, stream>>>(x, Wk, bk, kout, nullptr);
        gemm_bt<3, false, false><<<dim3(16, 32), 256, 0, stream>>>(x, Wv, bv, vout, nullptr);
        attn_stage<<<dim3(8, 64), 256, 0, stream>>>(Qbf, kout, vout, ctx);
        gemm_bt<2, true, false><<<dim3(16, 32), 256, 0, stream>>>(ctx, Wo, bo, outp, nullptr);
    }
}

// Round 4
// 569.053 us; speedup vs baseline: 1.2913x; 1.0713x over previous
//
#include <hip/hip_runtime.h>
#include <hip/hip_bf16.h>

typedef float f32x4 __attribute__((ext_vector_type(4)));
typedef __bf16 bf16x8 __attribute__((ext_vector_type(8)));
typedef unsigned short u16x8 __attribute__((ext_vector_type(8)));

// ---- constants: B=4, S=1024, dim=2048, H=16, D=128, T=1024, KV=2048, M=4096
#define DIMK 2048
#define QSCALE ((float)(0.08838834764831845 * 1.4426950408889634))  // 1/sqrt(128)*log2(e)

__device__ __forceinline__ unsigned short f2bf(float f) {
    union { float f; unsigned int u; } v; v.f = f;
    unsigned int r = v.u + 0x7fffu + ((v.u >> 16) & 1u);
    return (unsigned short)(r >> 16);
}
__device__ __forceinline__ float bf2f(unsigned short u) {
    union { unsigned int i; float f; } v; v.i = ((unsigned int)u) << 16; return v.f;
}

// async global->LDS 16B copy. LDS dest is wave-uniform base + lane*16.
__device__ __forceinline__ void lds_load16(void* lds, const void* gsrc) {
    __builtin_amdgcn_global_load_lds(
        (const __attribute__((address_space(1))) unsigned int*)gsrc,
        (__attribute__((address_space(3))) unsigned int*)lds,
        16, 0, 0);
}

// ================= prep kernels =================

// x + 4 weights -> bf16 (one launch). 6,291,456 f4 units.
__global__ __launch_bounds__(256) void conv_all(
    const float* __restrict__ x,  const float* __restrict__ Wq,
    const float* __restrict__ Wk, const float* __restrict__ Wv,
    const float* __restrict__ Wo,
    unsigned short* __restrict__ xbf, unsigned short* __restrict__ Wqb,
    unsigned short* __restrict__ Wkb, unsigned short* __restrict__ Wvb,
    unsigned short* __restrict__ Wob)
{
    int i = blockIdx.x * 256 + threadIdx.x;
    const float* src; unsigned short* dst; size_t off;
    if (i < 2097152) { src = x; dst = xbf; off = i; }
    else {
        int j = (i - 2097152) >> 20;
        off = (size_t)((i - 2097152) & 1048575);
        src = j == 0 ? Wq : j == 1 ? Wk : j == 2 ? Wv : Wo;
        dst = j == 0 ? Wqb : j == 1 ? Wkb : j == 2 ? Wvb : Wob;
    }
    f32x4 v = *(const f32x4*)(src + off * 4);
    ushort4 pk = { f2bf(v[0]), f2bf(v[1]), f2bf(v[2]), f2bf(v[3]) };
    *(ushort4*)(dst + off * 4) = pk;
}

// k_cache -> kout fp32 rows 0..1023 AND Kbf bf16 rows 0..1023
__global__ __launch_bounds__(256) void k_dual(
    const float* __restrict__ kc, float* __restrict__ kout, unsigned short* __restrict__ Kbf)
{
    size_t i4 = (size_t)blockIdx.x * 256 + threadIdx.x;
    size_t e = i4 * 4;
    size_t bh = e >> 17, rem = e & 131071;
    f32x4 v = *(const f32x4*)(kc + e);
    size_t dsto = (bh << 18) + rem;
    *(f32x4*)(kout + dsto) = v;
    ushort4 pk = { f2bf(v[0]), f2bf(v[1]), f2bf(v[2]), f2bf(v[3]) };
    *(ushort4*)(Kbf + dsto) = pk;
}

// v_cache -> vout fp32 rows 0..1023 AND Vtb bf16 transposed cols 0..1023
__global__ __launch_bounds__(256) void v_dual(
    const float* __restrict__ vc, float* __restrict__ vout, unsigned short* __restrict__ Vtb)
{
    __shared__ unsigned short T[128 * 72];
    const int kv0 = blockIdx.x * 64;
    const int bh = blockIdx.y;
    const int tid = threadIdx.x;
    const float* src = vc + ((size_t)bh << 17) + (size_t)kv0 * 128;
    float* vdst = vout + ((size_t)bh << 18) + (size_t)kv0 * 128;
    #pragma unroll
    for (int r = 0; r < 8; ++r) {
        int e4 = r * 256 + tid;
        int kv = e4 >> 5, d0 = (e4 & 31) << 2;
        f32x4 v = *(const f32x4*)(src + kv * 128 + d0);
        *(f32x4*)(vdst + kv * 128 + d0) = v;
        #pragma unroll
        for (int i = 0; i < 4; ++i) T[(d0 + i) * 72 + kv] = f2bf(v[i]);
    }
    __syncthreads();
    #pragma unroll
    for (int r = 0; r < 8; ++r) {
        int e = r * 256 + tid;
        int d = e >> 4, k4 = (e & 15) << 2;
        ushort4 pk = { T[d * 72 + k4], T[d * 72 + k4 + 1], T[d * 72 + k4 + 2], T[d * 72 + k4 + 3] };
        *(ushort4*)(Vtb + ((size_t)bh * 128 + d) * 2048 + kv0 + k4) = pk;
    }
}

// ================= GEMM core (m97 structure) =================
__device__ __forceinline__ void gemm_core(
    const unsigned short* __restrict__ A16, const unsigned short* __restrict__ W16,
    int m0, int n0, int tid, int w, int g, int c, int wr, int wc,
    unsigned short* As, unsigned short* Bs, f32x4 (&acc)[4][4])
{
    const int arow = tid >> 2;
    const int acol = (tid & 3) << 3;
    const unsigned short* Arow0 = A16 + (size_t)(m0 + arow) * DIMK + acol;
    const unsigned short* Arow1 = A16 + (size_t)(m0 + 64 + arow) * DIMK + acol;
    const unsigned short* Wrow0 = W16 + (size_t)(n0 + arow) * DIMK + acol;
    const unsigned short* Wrow1 = W16 + (size_t)(n0 + 64 + arow) * DIMK + acol;
    unsigned short* AsB0 = &As[(w * 64) * 8];
    unsigned short* AsB1 = &As[(256 + w * 64) * 8];
    unsigned short* BsB0 = &Bs[(w * 64) * 8];
    unsigned short* BsB1 = &Bs[(256 + w * 64) * 8];

    for (int k0 = 0; k0 < DIMK; k0 += 32) {
        __syncthreads();
        lds_load16(AsB0, Arow0 + k0);
        lds_load16(AsB1, Arow1 + k0);
        lds_load16(BsB0, Wrow0 + k0);
        lds_load16(BsB1, Wrow1 + k0);
        __syncthreads();

        bf16x8 af[4], bfr[4];
        #pragma unroll
        for (int i = 0; i < 4; ++i)
            af[i] = *(const bf16x8*)(&As[(wr * 64 + i * 16 + c) * 32 + g * 8]);
        #pragma unroll
        for (int i = 0; i < 4; ++i)
            bfr[i] = *(const bf16x8*)(&Bs[(wc * 64 + i * 16 + c) * 32 + g * 8]);
        #pragma unroll
        for (int i = 0; i < 4; ++i)
            #pragma unroll
            for (int j = 0; j < 4; ++j)
                acc[i][j] = __builtin_amdgcn_mfma_f32_16x16x32_bf16(af[i], bfr[j], acc[i][j], 0, 0, 0);
    }
}

// Fused Q/K/V projection GEMM. 1536 linear blocks, XCD-chunked n-panels.
__global__ __launch_bounds__(256) void gemm_qkv(
    const unsigned short* __restrict__ xbf,
    const unsigned short* __restrict__ Wqb, const unsigned short* __restrict__ Wkb,
    const unsigned short* __restrict__ Wvb,
    const float* __restrict__ bq, const float* __restrict__ bk, const float* __restrict__ bv,
    unsigned short* __restrict__ Qbf,
    float* __restrict__ kout, unsigned short* __restrict__ Kbf,
    float* __restrict__ vout, unsigned short* __restrict__ Vtb)
{
    const int o = blockIdx.x;
    const int xcd = o & 7;
    const int k = o >> 3;          // 0..191
    const int mblk = k & 31;
    const int nloc = k >> 5;       // 0..5
    const int nblk = xcd * 6 + nloc;   // 0..47
    const int m0 = mblk * 128;
    const int n0g = nblk * 128;
    const int mi = n0g >> 11;      // 0=Q,1=K,2=V
    const int n0 = n0g & 2047;

    const unsigned short* W16 = mi == 0 ? Wqb : (mi == 1 ? Wkb : Wvb);
    const float* bias = mi == 0 ? bq : (mi == 1 ? bk : bv);

    const int tid = threadIdx.x;
    const int lane = tid & 63;
    const int w = tid >> 6;
    const int g = lane >> 4;
    const int c = lane & 15;
    const int wr = w >> 1, wc = w & 1;

    __shared__ unsigned short As[128 * 32];
    __shared__ unsigned short Bs[128 * 32];

    f32x4 acc[4][4];
    #pragma unroll
    for (int i = 0; i < 4; ++i)
        #pragma unroll
        for (int j = 0; j < 4; ++j)
            acc[i][j] = f32x4{0.f, 0.f, 0.f, 0.f};

    gemm_core(xbf, W16, m0, n0, tid, w, g, c, wr, wc, As, Bs, acc);

    #pragma unroll
    for (int j = 0; j < 4; ++j) {
        const int n = n0 + wc * 64 + j * 16 + c;
        const float bn = bias[n];
        const int hh = n >> 7, d = n & 127;
        #pragma unroll
        for (int i = 0; i < 4; ++i) {
            float y4[4];
            #pragma unroll
            for (int tq = 0; tq < 4; ++tq) y4[tq] = acc[i][j][tq] + bn;
            const int mb = m0 + wr * 64 + i * 16 + g * 4;
            if (mi == 0) {
                #pragma unroll
                for (int tq = 0; tq < 4; ++tq) {
                    int m = mb + tq; int b = m >> 10, s = m & 1023;
                    Qbf[((((size_t)b * 16 + hh) << 10) + s) * 128 + d] = f2bf(y4[tq] * QSCALE);
                }
            } else if (mi == 1) {
                #pragma unroll
                for (int tq = 0; tq < 4; ++tq) {
                    int m = mb + tq; int b = m >> 10, s = m & 1023;
                    kout[(((size_t)b * 16 + hh) * 2048 + 1024 + s) * 128 + d] = y4[tq];
                    Kbf[(((size_t)b * 16 + hh) << 18) + (size_t)(1024 + s) * 128 + d] = f2bf(y4[tq]);
                }
            } else {
                #pragma unroll
                for (int tq = 0; tq < 4; ++tq) {
                    int m = mb + tq; int b = m >> 10, s = m & 1023;
                    vout[(((size_t)b * 16 + hh) * 2048 + 1024 + s) * 128 + d] = y4[tq];
                }
                int b = mb >> 10, s = mb & 1023;
                ushort4 pk = { f2bf(y4[0]), f2bf(y4[1]), f2bf(y4[2]), f2bf(y4[3]) };
                *(ushort4*)(Vtb + (((size_t)b * 16 + hh) * 128 + d) * 2048 + 1024 + s) = pk;
            }
        }
    }
}

// Output projection GEMM: out[m,n] = ctx[m,:] @ Wo[n,:] + bo. 512 linear blocks.
__global__ __launch_bounds__(256) void gemm_wo(
    const unsigned short* __restrict__ ctx, const unsigned short* __restrict__ Wob,
    const float* __restrict__ bo, float* __restrict__ outp)
{
    const int o = blockIdx.x;
    const int xcd = o & 7;
    const int k = o >> 3;          // 0..63
    const int mblk = k & 31;
    const int nloc = k >> 5;       // 0..1
    const int nblk = xcd * 2 + nloc;
    const int m0 = mblk * 128;
    const int n0 = nblk * 128;

    const int tid = threadIdx.x;
    const int lane = tid & 63;
    const int w = tid >> 6;
    const int g = lane >> 4;
    const int c = lane & 15;
    const int wr = w >> 1, wc = w & 1;

    __shared__ unsigned short As[128 * 32];
    __shared__ unsigned short Bs[128 * 32];

    f32x4 acc[4][4];
    #pragma unroll
    for (int i = 0; i < 4; ++i)
        #pragma unroll
        for (int j = 0; j < 4; ++j)
            acc[i][j] = f32x4{0.f, 0.f, 0.f, 0.f};

    gemm_core(ctx, Wob, m0, n0, tid, w, g, c, wr, wc, As, Bs, acc);

    #pragma unroll
    for (int j = 0; j < 4; ++j) {
        const int n = n0 + wc * 64 + j * 16 + c;
        const float bn = bo[n];
        #pragma unroll
        for (int i = 0; i < 4; ++i) {
            const int mb = m0 + wr * 64 + i * 16 + g * 4;
            #pragma unroll
            for (int tq = 0; tq < 4; ++tq)
                outp[(size_t)(mb + tq) * 2048 + n] = acc[i][j][tq] + bn;
        }
    }
}

// ================= flash attention v4: KV-split x2, XCD-grouped, LDS-staged =================
// 1024 linear blocks: xcd=o&7, half, qt (heavy-first), bh grouped per XCD.
// Outputs normalized bf16 partial ctx + (m,l) per row.
__global__ __launch_bounds__(256) void attn4(
    const unsigned short* __restrict__ Qbf,   // [B,H,1024,128] pre-scaled
    const unsigned short* __restrict__ Kbf,   // [B,H,2048,128]
    const unsigned short* __restrict__ Vtb,   // [B,H,128,2048]
    unsigned short* __restrict__ Pp,          // [2][64][1024][128] bf16
    float* __restrict__ Mp,                   // [2][64][1024]
    float* __restrict__ Lp)                   // [2][64][1024]
{
    const int o = blockIdx.x;
    const int xcd = o & 7;
    const int kk0 = o >> 3;                 // 0..127
    const int half = kk0 & 1;
    const int qt = 7 - ((kk0 >> 1) & 7);    // heavy blocks first within XCD
    const int bh = (kk0 >> 4) * 8 + xcd;

    const int tid = threadIdx.x;
    const int lane = tid & 63;
    const int w = tid >> 6;
    const int g = lane >> 4;
    const int c = lane & 15;

    __shared__ unsigned short Ks[64 * 128];   // [kv][d], XOR-swizzled (256B rows)
    __shared__ unsigned short Vs[128 * 64];   // [d][kv], XOR-swizzled (128B rows)
    __shared__ unsigned short Ps[4 * 32 * 72];

    const unsigned short* Qb = Qbf + ((size_t)bh * 1024 + qt * 128) * 128;
    const unsigned short* Kb = Kbf + ((size_t)bh << 18);
    const unsigned short* Vt = Vtb + ((size_t)bh << 18);

    bf16x8 aq[2][4];
    #pragma unroll
    for (int m2 = 0; m2 < 2; ++m2)
        #pragma unroll
        for (int kk = 0; kk < 4; ++kk)
            aq[m2][kk] = *(const bf16x8*)(Qb + (w * 32 + m2 * 16 + c) * 128 + kk * 32 + g * 8);

    f32x4 od[2][8];
    #pragma unroll
    for (int m2 = 0; m2 < 2; ++m2)
        #pragma unroll
        for (int nf = 0; nf < 8; ++nf)
            od[m2][nf] = f32x4{0.f, 0.f, 0.f, 0.f};
    float mrow[2][4], lrow[2][4];
    #pragma unroll
    for (int m2 = 0; m2 < 2; ++m2)
        #pragma unroll
        for (int j = 0; j < 4; ++j) { mrow[m2][j] = -1e30f; lrow[m2][j] = 0.f; }

    // staging constants
    const int krow = tid >> 4;
    const int kswz = (((tid & 15) << 4) ^ ((krow & 7) << 4)) >> 1;
    const int vrow = tid >> 3;
    const int vcolb = (tid & 7) << 4;
    const unsigned short* Kl = Kb + (size_t)krow * 128 + kswz;
    unsigned short* KsB = &Ks[(w * 64) * 8];
    unsigned short* VsB = &Vs[(w * 64) * 8];

    const int cnt = 9 + qt;
    const int t0 = half * cnt;
    const int lim_min = 1024 + qt * 128 + w * 32;
    unsigned short* Pw = &Ps[w * 32 * 72];

    for (int t = t0; t < t0 + cnt; ++t) {
        const int kv0 = t * 64;
        __syncthreads();
        #pragma unroll
        for (int r = 0; r < 4; ++r)
            lds_load16(KsB + r * 2048, Kl + (size_t)(kv0 + r * 16) * 128);
        #pragma unroll
        for (int r = 0; r < 4; ++r) {
            int row = vrow + r * 32;
            int swz = (vcolb ^ ((row & 7) << 4)) >> 1;
            lds_load16(VsB + r * 2048, Vt + (size_t)row * 2048 + kv0 + swz);
        }
        __syncthreads();

        // QK^T
        f32x4 sc[2][4];
        #pragma unroll
        for (int m2 = 0; m2 < 2; ++m2)
            #pragma unroll
            for (int n = 0; n < 4; ++n)
                sc[m2][n] = f32x4{0.f, 0.f, 0.f, 0.f};
        #pragma unroll
        for (int kk = 0; kk < 4; ++kk) {
            const int koff = ((kk * 64 + g * 16) ^ ((c & 7) << 4)) >> 1;
            bf16x8 bk[4];
            #pragma unroll
            for (int n = 0; n < 4; ++n)
                bk[n] = *(const bf16x8*)(&Ks[(n * 16 + c) * 128 + koff]);
            #pragma unroll
            for (int m2 = 0; m2 < 2; ++m2)
                #pragma unroll
                for (int n = 0; n < 4; ++n)
                    sc[m2][n] = __builtin_amdgcn_mfma_f32_16x16x32_bf16(aq[m2][kk], bk[n], sc[m2][n], 0, 0, 0);
        }

        // online softmax (exp2 domain), defer-max (T13)
        const bool need_mask = (kv0 + 63 > lim_min);
        #pragma unroll
        for (int m2 = 0; m2 < 2; ++m2) {
            #pragma unroll
            for (int j = 0; j < 4; ++j) {
                float rmax = -1e30f;
                if (need_mask) {
                    const int lim = lim_min + m2 * 16 + g * 4 + j;
                    #pragma unroll
                    for (int n = 0; n < 4; ++n) {
                        float s = sc[m2][n][j];
                        if (kv0 + n * 16 + c > lim) s = -1e30f;
                        sc[m2][n][j] = s;
                        rmax = fmaxf(rmax, s);
                    }
                } else {
                    #pragma unroll
                    for (int n = 0; n < 4; ++n)
                        rmax = fmaxf(rmax, sc[m2][n][j]);
                }
                #pragma unroll
                for (int off = 1; off < 16; off <<= 1)
                    rmax = fmaxf(rmax, __shfl_xor(rmax, off));
                float mold = mrow[m2][j];
                if (rmax > mold + 8.0f) {     // rescale only on real max growth
                    float fs = exp2f(mold - rmax);
                    mrow[m2][j] = rmax;
                    lrow[m2][j] *= fs;
                    #pragma unroll
                    for (int nf = 0; nf < 8; ++nf)
                        od[m2][nf][j] *= fs;
                }
                const float mm = mrow[m2][j];
                float rsum = 0.f;
                #pragma unroll
                for (int n = 0; n < 4; ++n) {
                    float p = exp2f(sc[m2][n][j] - mm);
                    sc[m2][n][j] = p;
                    rsum += p;
                }
                #pragma unroll
                for (int off = 1; off < 16; off <<= 1)
                    rsum += __shfl_xor(rsum, off);
                lrow[m2][j] += rsum;
            }
        }

        // P -> LDS (wave-private)
        #pragma unroll
        for (int m2 = 0; m2 < 2; ++m2)
            #pragma unroll
            for (int n = 0; n < 4; ++n)
                #pragma unroll
                for (int j = 0; j < 4; ++j)
                    Pw[(m2 * 16 + g * 4 + j) * 72 + n * 16 + c] = f2bf(sc[m2][n][j]);

        // PV
        #pragma unroll
        for (int kk = 0; kk < 2; ++kk) {
            const int voff = ((kk * 64 + g * 16) ^ ((c & 7) << 4)) >> 1;
            bf16x8 ap0 = *(const bf16x8*)(&Pw[c * 72 + kk * 32 + g * 8]);
            bf16x8 ap1 = *(const bf16x8*)(&Pw[(16 + c) * 72 + kk * 32 + g * 8]);
            #pragma unroll
            for (int nf = 0; nf < 8; ++nf) {
                bf16x8 bv = *(const bf16x8*)(&Vs[(nf * 16 + c) * 64 + voff]);
                od[0][nf] = __builtin_amdgcn_mfma_f32_16x16x32_bf16(ap0, bv, od[0][nf], 0, 0, 0);
                od[1][nf] = __builtin_amdgcn_mfma_f32_16x16x32_bf16(ap1, bv, od[1][nf], 0, 0, 0);
            }
        }
    }

    // partial epilogue: normalized od (bf16) + m,l
    const size_t pbase = ((size_t)(half * 64 + bh) * 1024 + qt * 128) * 128;
    const int mlbase = (half * 64 + bh) * 1024 + qt * 128;
    #pragma unroll
    for (int m2 = 0; m2 < 2; ++m2) {
        #pragma unroll
        for (int j = 0; j < 4; ++j) {
            const int ql = w * 32 + m2 * 16 + g * 4 + j;
            const float rl = 1.0f / lrow[m2][j];
            #pragma unroll
            for (int nf = 0; nf < 8; ++nf)
                Pp[pbase + (size_t)ql * 128 + nf * 16 + c] = f2bf(od[m2][nf][j] * rl);
            if (c == 0) {
                Mp[mlbase + ql] = mrow[m2][j];
                Lp[mlbase + ql] = lrow[m2][j];
            }
        }
    }
}

// merge the two KV-split partials -> ctx bf16
__global__ __launch_bounds__(256) void merge_ctx(
    const unsigned short* __restrict__ Pp, const float* __restrict__ Mp,
    const float* __restrict__ Lp, unsigned short* __restrict__ ctx)
{
    const int idx = blockIdx.x * 256 + threadIdx.x;   // 1,048,576
    const int r = idx >> 4;                 // bh*1024+q
    const int dc = (idx & 15) << 3;
    const float m0 = Mp[r], m1 = Mp[65536 + r];
    const float l0 = Lp[r], l1 = Lp[65536 + r];
    const float M = fmaxf(m0, m1);
    float w0 = l0 * exp2f(m0 - M);
    float w1 = l1 * exp2f(m1 - M);
    const float inv = 1.0f / (w0 + w1);
    w0 *= inv; w1 *= inv;
    u16x8 a = *(const u16x8*)(Pp + (size_t)r * 128 + dc);
    u16x8 bb = *(const u16x8*)(Pp + (size_t)8388608 + (size_t)r * 128 + dc);
    const int bh = r >> 10, q = r & 1023;
    unsigned short* dst = ctx + ((size_t)(bh >> 4) * 1024 + q) * 2048 + (bh & 15) * 128 + dc;
    u16x8 outv;
    #pragma unroll
    for (int e = 0; e < 8; ++e)
        outv[e] = f2bf(w0 * bf2f(a[e]) + w1 * bf2f(bb[e]));
    *(u16x8*)dst = outv;
}

// ================= small-ws fallback (round-1 style) =================
__global__ __launch_bounds__(256) void copy_cache(
    const float* __restrict__ kc, const float* __restrict__ vc,
    float* __restrict__ kout, float* __restrict__ vout)
{
    size_t i4 = (size_t)blockIdx.x * 256 + threadIdx.x;
    const float* src = blockIdx.y ? vc : kc;
    float* dst = blockIdx.y ? vout : kout;
    size_t e = i4 * 4;
    size_t bh = e >> 17, rem = e & 131071;
    f32x4 v = *(const f32x4*)(src + e);
    *(f32x4*)(dst + (bh << 18) + rem) = v;
}

template<int MODE, bool ABF16>
__global__ __launch_bounds__(256) void gemm_bt(
    const void* __restrict__ Ag, const float* __restrict__ Wf,
    const float* __restrict__ bias, void* __restrict__ dst)
{
    const int tid = threadIdx.x;
    const int lane = tid & 63;
    const int w = tid >> 6;
    const int g = lane >> 4;
    const int c = lane & 15;
    const int wr = w >> 1, wc = w & 1;
    const int m0 = blockIdx.y * 128;
    const int n0 = blockIdx.x * 128;

    __shared__ unsigned short As[128 * 40];
    __shared__ unsigned short Bs[128 * 40];

    f32x4 acc[4][4];
    #pragma unroll
    for (int i = 0; i < 4; ++i)
        #pragma unroll
        for (int j = 0; j < 4; ++j)
            acc[i][j] = f32x4{0.f, 0.f, 0.f, 0.f};

    for (int k0 = 0; k0 < DIMK; k0 += 32) {
        __syncthreads();
        if constexpr (ABF16) {
            const unsigned short* A16 = (const unsigned short*)Ag;
            #pragma unroll
            for (int r = 0; r < 2; ++r) {
                int e8 = r * 256 + tid;
                int row = e8 >> 2, col = (e8 & 3) << 3;
                *(uint4*)(&As[row * 40 + col]) =
                    *(const uint4*)(A16 + (size_t)(m0 + row) * DIMK + k0 + col);
            }
        } else {
            const float* Af = (const float*)Ag;
            #pragma unroll
            for (int r = 0; r < 4; ++r) {
                int e4 = r * 256 + tid;
                int row = e4 >> 3, col = (e4 & 7) << 2;
                f32x4 v = *(const f32x4*)(Af + (size_t)(m0 + row) * DIMK + k0 + col);
                ushort4 pk = { f2bf(v[0]), f2bf(v[1]), f2bf(v[2]), f2bf(v[3]) };
                *(ushort4*)(&As[row * 40 + col]) = pk;
            }
        }
        {
            #pragma unroll
            for (int r = 0; r < 4; ++r) {
                int e4 = r * 256 + tid;
                int row = e4 >> 3, col = (e4 & 7) << 2;
                f32x4 v = *(const f32x4*)(Wf + (size_t)(n0 + row) * DIMK + k0 + col);
                ushort4 pk = { f2bf(v[0]), f2bf(v[1]), f2bf(v[2]), f2bf(v[3]) };
                *(ushort4*)(&Bs[row * 40 + col]) = pk;
            }
        }
        __syncthreads();

        bf16x8 af[4], bfr[4];
        #pragma unroll
        for (int i = 0; i < 4; ++i)
            af[i] = *(const bf16x8*)(&As[(wr * 64 + i * 16 + c) * 40 + g * 8]);
        #pragma unroll
        for (int i = 0; i < 4; ++i)
            bfr[i] = *(const bf16x8*)(&Bs[(wc * 64 + i * 16 + c) * 40 + g * 8]);
        #pragma unroll
        for (int i = 0; i < 4; ++i)
            #pragma unroll
            for (int j = 0; j < 4; ++j)
                acc[i][j] = __builtin_amdgcn_mfma_f32_16x16x32_bf16(af[i], bfr[j], acc[i][j], 0, 0, 0);
    }

    #pragma unroll
    for (int j = 0; j < 4; ++j) {
        const int n = n0 + wc * 64 + j * 16 + c;
        const float bn = bias[n];
        #pragma unroll
        for (int i = 0; i < 4; ++i) {
            float y4[4];
            #pragma unroll
            for (int tq = 0; tq < 4; ++tq) y4[tq] = acc[i][j][tq] + bn;
            const int mb = m0 + wr * 64 + i * 16 + g * 4;
            if constexpr (MODE == 0) {
                #pragma unroll
                for (int tq = 0; tq < 4; ++tq) {
                    int m = mb + tq; int b = m >> 10, s = m & 1023;
                    int hh = n >> 7, d = n & 127;
                    ((unsigned short*)dst)[((((size_t)b * 16 + hh) << 10) + s) * 128 + d] = f2bf(y4[tq] * QSCALE);
                }
            } else if constexpr (MODE == 1) {
                #pragma unroll
                for (int tq = 0; tq < 4; ++tq) {
                    int m = mb + tq; int b = m >> 10, s = m & 1023;
                    int hh = n >> 7, d = n & 127;
                    ((float*)dst)[(((size_t)b * 16 + hh) * 2048 + 1024 + s) * 128 + d] = y4[tq];
                }
            } else {
                #pragma unroll
                for (int tq = 0; tq < 4; ++tq)
                    ((float*)dst)[(size_t)(mb + tq) * 2048 + n] = y4[tq];
            }
        }
    }
}

__global__ __launch_bounds__(256) void attn_stage(
    const unsigned short* __restrict__ Qbf,
    const float* __restrict__ Kf, const float* __restrict__ Vf,
    unsigned short* __restrict__ ctx)
{
    const int qt = blockIdx.x;
    const int bh = blockIdx.y;
    const int b = bh >> 4, h = bh & 15;
    const int tid = threadIdx.x;
    const int lane = tid & 63;
    const int w = tid >> 6;
    const int g = lane >> 4;
    const int c = lane & 15;

    __shared__ unsigned short Ksl[64 * 136];
    __shared__ unsigned short Vtl[128 * 72];
    __shared__ unsigned short Ps[4 * 32 * 72];

    bf16x8 aq[2][4];
    const unsigned short* Qb = Qbf + ((size_t)bh * 1024 + qt * 128) * 128;
    #pragma unroll
    for (int m2 = 0; m2 < 2; ++m2)
        #pragma unroll
        for (int kk = 0; kk < 4; ++kk)
            aq[m2][kk] = *(const bf16x8*)(Qb + (w * 32 + m2 * 16 + c) * 128 + kk * 32 + g * 8);

    f32x4 od[2][8];
    #pragma unroll
    for (int m2 = 0; m2 < 2; ++m2)
        #pragma unroll
        for (int nf = 0; nf < 8; ++nf)
            od[m2][nf] = f32x4{0.f, 0.f, 0.f, 0.f};
    float mrow[2][4], lrow[2][4];
    #pragma unroll
    for (int m2 = 0; m2 < 2; ++m2)
        #pragma unroll
        for (int j = 0; j < 4; ++j) { mrow[m2][j] = -1e30f; lrow[m2][j] = 0.f; }

    const float* Kb = Kf + (size_t)bh * 2048 * 128;
    const float* Vb = Vf + (size_t)bh * 2048 * 128;
    const int ntiles = 18 + 2 * qt;

    for (int t = 0; t < ntiles; ++t) {
        __syncthreads();
        const float* Kt = Kb + (size_t)t * 64 * 128;
        #pragma unroll
        for (int r = 0; r < 8; ++r) {
            int e4 = r * 256 + tid;
            int kv = e4 >> 5, d0 = (e4 & 31) << 2;
            f32x4 v = *(const f32x4*)(Kt + kv * 128 + d0);
            ushort4 pk = { f2bf(v[0]), f2bf(v[1]), f2bf(v[2]), f2bf(v[3]) };
            *(ushort4*)(&Ksl[kv * 136 + d0]) = pk;
        }
        const float* Vg = Vb + (size_t)t * 64 * 128;
        #pragma unroll
        for (int r = 0; r < 8; ++r) {
            int e4 = tid * 8 + r;
            int kv = e4 >> 5, d0 = (e4 & 31) << 2;
            f32x4 v = *(const f32x4*)(Vg + kv * 128 + d0);
            #pragma unroll
            for (int i = 0; i < 4; ++i)
                Vtl[(d0 + i) * 72 + kv] = f2bf(v[i]);
        }
        __syncthreads();

        f32x4 sc[2][4];
        #pragma unroll
        for (int m2 = 0; m2 < 2; ++m2)
            #pragma unroll
            for (int n = 0; n < 4; ++n)
                sc[m2][n] = f32x4{0.f, 0.f, 0.f, 0.f};
        #pragma unroll
        for (int kk = 0; kk < 4; ++kk) {
            bf16x8 bk[4];
            #pragma unroll
            for (int n = 0; n < 4; ++n)
                bk[n] = *(const bf16x8*)(&Ksl[(n * 16 + c) * 136 + kk * 32 + g * 8]);
            #pragma unroll
            for (int m2 = 0; m2 < 2; ++m2)
                #pragma unroll
                for (int n = 0; n < 4; ++n)
                    sc[m2][n] = __builtin_amdgcn_mfma_f32_16x16x32_bf16(aq[m2][kk], bk[n], sc[m2][n], 0, 0, 0);
        }

        const int kvbase = t * 64;
        #pragma unroll
        for (int m2 = 0; m2 < 2; ++m2) {
            #pragma unroll
            for (int j = 0; j < 4; ++j) {
                const int qg = qt * 128 + w * 32 + m2 * 16 + g * 4 + j;
                const int lim = qg + 1024;
                float rmax = -1e30f;
                #pragma unroll
                for (int n = 0; n < 4; ++n) {
                    float s = sc[m2][n][j] * QSCALE;
                    if (kvbase + n * 16 + c > lim) s = -1e30f;
                    sc[m2][n][j] = s;
                    rmax = fmaxf(rmax, s);
                }
                #pragma unroll
                for (int off = 1; off < 16; off <<= 1)
                    rmax = fmaxf(rmax, __shfl_xor(rmax, off));
                float mold = mrow[m2][j];
                float mnew = fmaxf(mold, rmax);
                mrow[m2][j] = mnew;
                float fs = exp2f(mold - mnew);
                float rsum = 0.f;
                #pragma unroll
                for (int n = 0; n < 4; ++n) {
                    float p = exp2f(sc[m2][n][j] - mnew);
                    sc[m2][n][j] = p;
                    rsum += p;
                }
                #pragma unroll
                for (int off = 1; off < 16; off <<= 1)
                    rsum += __shfl_xor(rsum, off);
                lrow[m2][j] = lrow[m2][j] * fs + rsum;
                #pragma unroll
                for (int nf = 0; nf < 8; ++nf)
                    od[m2][nf][j] *= fs;
            }
        }

        unsigned short* Pw = &Ps[w * 32 * 72];
        #pragma unroll
        for (int m2 = 0; m2 < 2; ++m2)
            #pragma unroll
            for (int n = 0; n < 4; ++n)
                #pragma unroll
                for (int j = 0; j < 4; ++j)
                    Pw[(m2 * 16 + g * 4 + j) * 72 + n * 16 + c] = f2bf(sc[m2][n][j]);

        #pragma unroll
        for (int kk = 0; kk < 2; ++kk) {
            bf16x8 ap0 = *(const bf16x8*)(&Ps[(w * 32 + c) * 72 + kk * 32 + g * 8]);
            bf16x8 ap1 = *(const bf16x8*)(&Ps[(w * 32 + 16 + c) * 72 + kk * 32 + g * 8]);
            #pragma unroll
            for (int nf = 0; nf < 8; ++nf) {
                bf16x8 bv = *(const bf16x8*)(&Vtl[(nf * 16 + c) * 72 + kk * 32 + g * 8]);
                od[0][nf] = __builtin_amdgcn_mfma_f32_16x16x32_bf16(ap0, bv, od[0][nf], 0, 0, 0);
                od[1][nf] = __builtin_amdgcn_mfma_f32_16x16x32_bf16(ap1, bv, od[1][nf], 0, 0, 0);
            }
        }
    }

    #pragma unroll
    for (int m2 = 0; m2 < 2; ++m2) {
        #pragma unroll
        for (int j = 0; j < 4; ++j) {
            const int qg = qt * 128 + w * 32 + m2 * 16 + g * 4 + j;
            const float rl = 1.0f / lrow[m2][j];
            #pragma unroll
            for (int nf = 0; nf < 8; ++nf) {
                const int d = nf * 16 + c;
                ctx[((size_t)b * 1024 + qg) * 2048 + h * 128 + d] = f2bf(od[m2][nf][j] * rl);
            }
        }
    }
}

extern "C" void kernel_launch(void* const* d_in, const int* in_sizes, int n_in,
                              void* d_out, int out_size, void* d_ws, size_t ws_size,
                              hipStream_t stream) {
    const float* x  = (const float*)d_in[0];
    const float* kc = (const float*)d_in[1];
    const float* vc = (const float*)d_in[2];
    const float* Wq = (const float*)d_in[3];
    const float* bq = (const float*)d_in[4];
    const float* Wk = (const float*)d_in[5];
    const float* bk = (const float*)d_in[6];
    const float* Wv = (const float*)d_in[7];
    const float* bv = (const float*)d_in[8];
    const float* Wo = (const float*)d_in[9];
    const float* bo = (const float*)d_in[10];

    float* outp = (float*)d_out;
    float* kout = outp + (size_t)8388608;   // k region [4,16,2048,128]
    float* vout = outp + (size_t)25165824;  // v region

    // ws layout (ushort units)
    unsigned short* Qbf = (unsigned short*)d_ws;          //  8,388,608
    unsigned short* ctx = Qbf + (size_t)8388608;          //  8,388,608
    unsigned short* Kbf = ctx + (size_t)8388608;          // 16,777,216
    unsigned short* Vtb = Kbf + (size_t)16777216;         // 16,777,216
    unsigned short* xbf = Vtb + (size_t)16777216;         //  8,388,608
    unsigned short* Wqb = xbf + (size_t)8388608;          //  4,194,304 each
    unsigned short* Wkb = Wqb + (size_t)4194304;
    unsigned short* Wvb = Wkb + (size_t)4194304;
    unsigned short* Wob = Wvb + (size_t)4194304;
    // after gemm_qkv completes, xbf/Wqb/Wkb are reused as attention partials:
    unsigned short* Pp = xbf;                             // [2][64][1024][128] bf16
    float* Mp = (float*)Wvb;                              // [2][64][1024]
    float* Lp = Mp + (size_t)131072;

    const bool full = ws_size >= (size_t)150994944;

    if (full) {
        conv_all<<<24576, 256, 0, stream>>>(x, Wq, Wk, Wv, Wo, xbf, Wqb, Wkb, Wvb, Wob);
        k_dual<<<8192, 256, 0, stream>>>(kc, kout, Kbf);
        v_dual<<<dim3(16, 64), 256, 0, stream>>>(vc, vout, Vtb);
        gemm_qkv<<<1536, 256, 0, stream>>>(xbf, Wqb, Wkb, Wvb, bq, bk, bv,
                                           Qbf, kout, Kbf, vout, Vtb);
        attn4<<<1024, 256, 0, stream>>>(Qbf, Kbf, Vtb, Pp, Mp, Lp);
        merge_ctx<<<4096, 256, 0, stream>>>(Pp, Mp, Lp, ctx);
        gemm_wo<<<512, 256, 0, stream>>>(ctx, Wob, bo, outp);
    } else {
        copy_cache<<<dim3(8192, 2), 256, 0, stream>>>(kc, vc, kout, vout);
        gemm_bt<0, false><<<dim3(16, 32), 256, 0, stream>>>(x, Wq, bq, Qbf);
        gemm_bt<1, false><<<dim3(16, 32), 256, 0, stream>>>(x, Wk, bk, kout);
        gemm_bt<1, false><<<dim3(16, 32), 256, 0, stream>>>(x, Wv, bv, vout);
        attn_stage<<<dim3(8, 64), 256, 0, stream>>>(Qbf, kout, vout, ctx);
        gemm_bt<2, true><<<dim3(16, 32), 256, 0, stream>>>(ctx, Wo, bo, outp);
    }
}

// Round 5
// 448.569 us; speedup vs baseline: 1.6381x; 1.2686x over previous
//
#include <hip/hip_runtime.h>
#include <hip/hip_bf16.h>

typedef float f32x4 __attribute__((ext_vector_type(4)));
typedef __bf16 bf16x8 __attribute__((ext_vector_type(8)));
typedef unsigned short u16x8 __attribute__((ext_vector_type(8)));

// ---- constants: B=4, S=1024, dim=2048, H=16, D=128, T=1024, KV=2048, M=4096
#define DIMK 2048
#define QSCALE ((float)(0.08838834764831845 * 1.4426950408889634))  // 1/sqrt(128)*log2(e)

__device__ __forceinline__ unsigned short f2bf(float f) {
    union { float f; unsigned int u; } v; v.f = f;
    unsigned int r = v.u + 0x7fffu + ((v.u >> 16) & 1u);
    return (unsigned short)(r >> 16);
}
__device__ __forceinline__ float bf2f(unsigned short u) {
    union { unsigned int i; float f; } v; v.i = ((unsigned int)u) << 16; return v.f;
}

// async global->LDS 16B copy. LDS dest is wave-uniform base + lane*16.
__device__ __forceinline__ void lds_load16(void* lds, const void* gsrc) {
    __builtin_amdgcn_global_load_lds(
        (const __attribute__((address_space(1))) unsigned int*)gsrc,
        (__attribute__((address_space(3))) unsigned int*)lds,
        16, 0, 0);
}

// ================= prep kernels =================

__global__ __launch_bounds__(256) void conv_all(
    const float* __restrict__ x,  const float* __restrict__ Wq,
    const float* __restrict__ Wk, const float* __restrict__ Wv,
    const float* __restrict__ Wo,
    unsigned short* __restrict__ xbf, unsigned short* __restrict__ Wqb,
    unsigned short* __restrict__ Wkb, unsigned short* __restrict__ Wvb,
    unsigned short* __restrict__ Wob)
{
    int i = blockIdx.x * 256 + threadIdx.x;
    const float* src; unsigned short* dst; size_t off;
    if (i < 2097152) { src = x; dst = xbf; off = i; }
    else {
        int j = (i - 2097152) >> 20;
        off = (size_t)((i - 2097152) & 1048575);
        src = j == 0 ? Wq : j == 1 ? Wk : j == 2 ? Wv : Wo;
        dst = j == 0 ? Wqb : j == 1 ? Wkb : j == 2 ? Wvb : Wob;
    }
    f32x4 v = *(const f32x4*)(src + off * 4);
    ushort4 pk = { f2bf(v[0]), f2bf(v[1]), f2bf(v[2]), f2bf(v[3]) };
    *(ushort4*)(dst + off * 4) = pk;
}

__global__ __launch_bounds__(256) void k_dual(
    const float* __restrict__ kc, float* __restrict__ kout, unsigned short* __restrict__ Kbf)
{
    size_t i4 = (size_t)blockIdx.x * 256 + threadIdx.x;
    size_t e = i4 * 4;
    size_t bh = e >> 17, rem = e & 131071;
    f32x4 v = *(const f32x4*)(kc + e);
    size_t dsto = (bh << 18) + rem;
    *(f32x4*)(kout + dsto) = v;
    ushort4 pk = { f2bf(v[0]), f2bf(v[1]), f2bf(v[2]), f2bf(v[3]) };
    *(ushort4*)(Kbf + dsto) = pk;
}

__global__ __launch_bounds__(256) void v_dual(
    const float* __restrict__ vc, float* __restrict__ vout, unsigned short* __restrict__ Vtb)
{
    __shared__ unsigned short T[128 * 72];
    const int kv0 = blockIdx.x * 64;
    const int bh = blockIdx.y;
    const int tid = threadIdx.x;
    const float* src = vc + ((size_t)bh << 17) + (size_t)kv0 * 128;
    float* vdst = vout + ((size_t)bh << 18) + (size_t)kv0 * 128;
    #pragma unroll
    for (int r = 0; r < 8; ++r) {
        int e4 = r * 256 + tid;
        int kv = e4 >> 5, d0 = (e4 & 31) << 2;
        f32x4 v = *(const f32x4*)(src + kv * 128 + d0);
        *(f32x4*)(vdst + kv * 128 + d0) = v;
        #pragma unroll
        for (int i = 0; i < 4; ++i) T[(d0 + i) * 72 + kv] = f2bf(v[i]);
    }
    __syncthreads();
    #pragma unroll
    for (int r = 0; r < 8; ++r) {
        int e = r * 256 + tid;
        int d = e >> 4, k4 = (e & 15) << 2;
        ushort4 pk = { T[d * 72 + k4], T[d * 72 + k4 + 1], T[d * 72 + k4 + 2], T[d * 72 + k4 + 3] };
        *(ushort4*)(Vtb + ((size_t)bh * 128 + d) * 2048 + kv0 + k4) = pk;
    }
}

// ================= GEMM core (m97 structure) =================
__device__ __forceinline__ void gemm_core(
    const unsigned short* __restrict__ A16, const unsigned short* __restrict__ W16,
    int m0, int n0, int tid, int w, int g, int c, int wr, int wc,
    unsigned short* As, unsigned short* Bs, f32x4 (&acc)[4][4])
{
    const int arow = tid >> 2;
    const int acol = (tid & 3) << 3;
    const unsigned short* Arow0 = A16 + (size_t)(m0 + arow) * DIMK + acol;
    const unsigned short* Arow1 = A16 + (size_t)(m0 + 64 + arow) * DIMK + acol;
    const unsigned short* Wrow0 = W16 + (size_t)(n0 + arow) * DIMK + acol;
    const unsigned short* Wrow1 = W16 + (size_t)(n0 + 64 + arow) * DIMK + acol;
    unsigned short* AsB0 = &As[(w * 64) * 8];
    unsigned short* AsB1 = &As[(256 + w * 64) * 8];
    unsigned short* BsB0 = &Bs[(w * 64) * 8];
    unsigned short* BsB1 = &Bs[(256 + w * 64) * 8];

    for (int k0 = 0; k0 < DIMK; k0 += 32) {
        __syncthreads();
        lds_load16(AsB0, Arow0 + k0);
        lds_load16(AsB1, Arow1 + k0);
        lds_load16(BsB0, Wrow0 + k0);
        lds_load16(BsB1, Wrow1 + k0);
        __syncthreads();

        bf16x8 af[4], bfr[4];
        #pragma unroll
        for (int i = 0; i < 4; ++i)
            af[i] = *(const bf16x8*)(&As[(wr * 64 + i * 16 + c) * 32 + g * 8]);
        #pragma unroll
        for (int i = 0; i < 4; ++i)
            bfr[i] = *(const bf16x8*)(&Bs[(wc * 64 + i * 16 + c) * 32 + g * 8]);
        #pragma unroll
        for (int i = 0; i < 4; ++i)
            #pragma unroll
            for (int j = 0; j < 4; ++j)
                acc[i][j] = __builtin_amdgcn_mfma_f32_16x16x32_bf16(af[i], bfr[j], acc[i][j], 0, 0, 0);
    }
}

// Fused Q/K/V projection GEMM. 1536 linear blocks, XCD-chunked n-panels.
__global__ __launch_bounds__(256) void gemm_qkv(
    const unsigned short* __restrict__ xbf,
    const unsigned short* __restrict__ Wqb, const unsigned short* __restrict__ Wkb,
    const unsigned short* __restrict__ Wvb,
    const float* __restrict__ bq, const float* __restrict__ bk, const float* __restrict__ bv,
    unsigned short* __restrict__ Qbf,
    float* __restrict__ kout, unsigned short* __restrict__ Kbf,
    float* __restrict__ vout, unsigned short* __restrict__ Vtb)
{
    const int o = blockIdx.x;
    const int xcd = o & 7;
    const int k = o >> 3;
    const int mblk = k & 31;
    const int nloc = k >> 5;
    const int nblk = xcd * 6 + nloc;
    const int m0 = mblk * 128;
    const int n0g = nblk * 128;
    const int mi = n0g >> 11;
    const int n0 = n0g & 2047;

    const unsigned short* W16 = mi == 0 ? Wqb : (mi == 1 ? Wkb : Wvb);
    const float* bias = mi == 0 ? bq : (mi == 1 ? bk : bv);

    const int tid = threadIdx.x;
    const int lane = tid & 63;
    const int w = tid >> 6;
    const int g = lane >> 4;
    const int c = lane & 15;
    const int wr = w >> 1, wc = w & 1;

    __shared__ unsigned short As[128 * 32];
    __shared__ unsigned short Bs[128 * 32];

    f32x4 acc[4][4];
    #pragma unroll
    for (int i = 0; i < 4; ++i)
        #pragma unroll
        for (int j = 0; j < 4; ++j)
            acc[i][j] = f32x4{0.f, 0.f, 0.f, 0.f};

    gemm_core(xbf, W16, m0, n0, tid, w, g, c, wr, wc, As, Bs, acc);

    #pragma unroll
    for (int j = 0; j < 4; ++j) {
        const int n = n0 + wc * 64 + j * 16 + c;
        const float bn = bias[n];
        const int hh = n >> 7, d = n & 127;
        #pragma unroll
        for (int i = 0; i < 4; ++i) {
            float y4[4];
            #pragma unroll
            for (int tq = 0; tq < 4; ++tq) y4[tq] = acc[i][j][tq] + bn;
            const int mb = m0 + wr * 64 + i * 16 + g * 4;
            if (mi == 0) {
                #pragma unroll
                for (int tq = 0; tq < 4; ++tq) {
                    int m = mb + tq; int b = m >> 10, s = m & 1023;
                    Qbf[((((size_t)b * 16 + hh) << 10) + s) * 128 + d] = f2bf(y4[tq] * QSCALE);
                }
            } else if (mi == 1) {
                #pragma unroll
                for (int tq = 0; tq < 4; ++tq) {
                    int m = mb + tq; int b = m >> 10, s = m & 1023;
                    kout[(((size_t)b * 16 + hh) * 2048 + 1024 + s) * 128 + d] = y4[tq];
                    Kbf[(((size_t)b * 16 + hh) << 18) + (size_t)(1024 + s) * 128 + d] = f2bf(y4[tq]);
                }
            } else {
                #pragma unroll
                for (int tq = 0; tq < 4; ++tq) {
                    int m = mb + tq; int b = m >> 10, s = m & 1023;
                    vout[(((size_t)b * 16 + hh) * 2048 + 1024 + s) * 128 + d] = y4[tq];
                }
                int b = mb >> 10, s = mb & 1023;
                ushort4 pk = { f2bf(y4[0]), f2bf(y4[1]), f2bf(y4[2]), f2bf(y4[3]) };
                *(ushort4*)(Vtb + (((size_t)b * 16 + hh) * 128 + d) * 2048 + 1024 + s) = pk;
            }
        }
    }
}

// Output projection GEMM. 512 linear blocks.
__global__ __launch_bounds__(256) void gemm_wo(
    const unsigned short* __restrict__ ctx, const unsigned short* __restrict__ Wob,
    const float* __restrict__ bo, float* __restrict__ outp)
{
    const int o = blockIdx.x;
    const int xcd = o & 7;
    const int k = o >> 3;
    const int mblk = k & 31;
    const int nloc = k >> 5;
    const int nblk = xcd * 2 + nloc;
    const int m0 = mblk * 128;
    const int n0 = nblk * 128;

    const int tid = threadIdx.x;
    const int lane = tid & 63;
    const int w = tid >> 6;
    const int g = lane >> 4;
    const int c = lane & 15;
    const int wr = w >> 1, wc = w & 1;

    __shared__ unsigned short As[128 * 32];
    __shared__ unsigned short Bs[128 * 32];

    f32x4 acc[4][4];
    #pragma unroll
    for (int i = 0; i < 4; ++i)
        #pragma unroll
        for (int j = 0; j < 4; ++j)
            acc[i][j] = f32x4{0.f, 0.f, 0.f, 0.f};

    gemm_core(ctx, Wob, m0, n0, tid, w, g, c, wr, wc, As, Bs, acc);

    #pragma unroll
    for (int j = 0; j < 4; ++j) {
        const int n = n0 + wc * 64 + j * 16 + c;
        const float bn = bo[n];
        #pragma unroll
        for (int i = 0; i < 4; ++i) {
            const int mb = m0 + wr * 64 + i * 16 + g * 4;
            #pragma unroll
            for (int tq = 0; tq < 4; ++tq)
                outp[(size_t)(mb + tq) * 2048 + n] = acc[i][j][tq] + bn;
        }
    }
}

// ================= flash attention v5 =================
// Swapped QK^T (lane-local q rows), in-register P->PV A-frags via permuted V staging,
// double-buffered K (global_load_lds) + V (reg-staged), ONE barrier per tile.
// 1024 blocks: KV-split x2, XCD-grouped bh, heavy-qt-first.
__global__ __launch_bounds__(256) void attn5(
    const unsigned short* __restrict__ Qbf,   // [B,H,1024,128] pre-scaled
    const unsigned short* __restrict__ Kbf,   // [B,H,2048,128]
    const unsigned short* __restrict__ Vtb,   // [B,H,128,2048]
    unsigned short* __restrict__ Pp,          // [2][64][1024][128] bf16 normalized partials
    float* __restrict__ Mp,                   // [2][64][1024]
    float* __restrict__ Lp)                   // [2][64][1024]
{
    const int o = blockIdx.x;
    const int xcd = o & 7;
    const int kk0 = o >> 3;
    const int half = kk0 & 1;
    const int qt = 7 - ((kk0 >> 1) & 7);
    const int bh = (kk0 >> 4) * 8 + xcd;

    const int tid = threadIdx.x;
    const int lane = tid & 63;
    const int w = tid >> 6;
    const int g = lane >> 4;
    const int c = lane & 15;
    const int cswz = (c & 7) << 3;            // element-XOR for swizzled LDS reads

    __shared__ unsigned short Ks[2][64 * 128];   // [kv][d], src-pre-swizzled
    __shared__ unsigned short Vs[2][128 * 64];   // [d][p], permuted + XOR-swizzled

    const unsigned short* Qb = Qbf + ((size_t)bh * 1024 + qt * 128) * 128;
    const unsigned short* Kb = Kbf + ((size_t)bh << 18);
    const unsigned short* Vt = Vtb + ((size_t)bh << 18);

    // Q fragments (B-operand): col=c -> q = w*32+m2*16+c, k = d = kd*32+g*8+e
    bf16x8 aq[2][4];
    #pragma unroll
    for (int m2 = 0; m2 < 2; ++m2)
        #pragma unroll
        for (int kd = 0; kd < 4; ++kd)
            aq[m2][kd] = *(const bf16x8*)(Qb + (w * 32 + m2 * 16 + c) * 128 + kd * 32 + g * 8);

    f32x4 od[2][8];
    #pragma unroll
    for (int m2 = 0; m2 < 2; ++m2)
        #pragma unroll
        for (int nf = 0; nf < 8; ++nf)
            od[m2][nf] = f32x4{0.f, 0.f, 0.f, 0.f};
    float mrow[2] = { -1e30f, -1e30f };
    float lrow[2] = { 0.f, 0.f };

    // K staging: pre-swizzled global source, linear LDS dest
    const int krow = tid >> 4;                                    // +16 per issue
    const int kswz = (((tid & 15) << 4) ^ ((krow & 7) << 4)) >> 1;
    const unsigned short* Kl = Kb + (size_t)krow * 128 + kswz;

    // V staging: permuted positions. chunk: d = vd + r*32, kv base = ck*8.
    // kv = kk*32 + a*16 + gv*4 + j  ->  p = kk*32 + gv*8 + a*4 + j
    const int vd = tid >> 3;           // 0..31
    const int ck = tid & 7;
    const int kkv = ck >> 2;
    const int av = (ck >> 1) & 1;
    const int p0 = kkv * 32 + (((2 * ck) & 3) << 3) + av * 4;
    const int p1 = kkv * 32 + (((2 * ck + 1) & 3) << 3) + av * 4;

    const int cnt = 9 + qt;
    const int t0 = half * cnt;
    const int lim_min = 1024 + qt * 128 + w * 32;

    u16x8 vreg0, vreg1, vreg2, vreg3;

    // ---- prologue: stage tile t0 into buffer 0 ----
    {
        const int kv0 = t0 * 64;
        #pragma unroll
        for (int r = 0; r < 4; ++r)
            lds_load16(&Ks[0][w * 512 + r * 2048], Kl + (size_t)(kv0 + r * 16) * 128);
        vreg0 = *(const u16x8*)(Vt + (size_t)(vd +  0) * 2048 + kv0 + ck * 8);
        vreg1 = *(const u16x8*)(Vt + (size_t)(vd + 32) * 2048 + kv0 + ck * 8);
        vreg2 = *(const u16x8*)(Vt + (size_t)(vd + 64) * 2048 + kv0 + ck * 8);
        vreg3 = *(const u16x8*)(Vt + (size_t)(vd + 96) * 2048 + kv0 + ck * 8);
        #pragma unroll
        for (int r = 0; r < 4; ++r) {
            const int d = vd + r * 32;
            const int sw = (d & 7) << 3;
            unsigned short* row = &Vs[0][d * 64];
            u16x8 vv = r == 0 ? vreg0 : r == 1 ? vreg1 : r == 2 ? vreg2 : vreg3;
            ushort4 lo = { vv[0], vv[1], vv[2], vv[3] };
            ushort4 hi = { vv[4], vv[5], vv[6], vv[7] };
            *(ushort4*)(&row[p0 ^ sw]) = lo;
            *(ushort4*)(&row[p1 ^ sw]) = hi;
        }
        __syncthreads();
    }

    int cur = 0;
    for (int t = t0; t < t0 + cnt; ++t) {
        const int kv0 = t * 64;
        const bool next = (t + 1 < t0 + cnt);

        // ---- issue next tile's loads (hidden under this tile's compute) ----
        if (next) {
            const int kvn = kv0 + 64;
            #pragma unroll
            for (int r = 0; r < 4; ++r)
                lds_load16(&Ks[cur ^ 1][w * 512 + r * 2048], Kl + (size_t)(kvn + r * 16) * 128);
            vreg0 = *(const u16x8*)(Vt + (size_t)(vd +  0) * 2048 + kvn + ck * 8);
            vreg1 = *(const u16x8*)(Vt + (size_t)(vd + 32) * 2048 + kvn + ck * 8);
            vreg2 = *(const u16x8*)(Vt + (size_t)(vd + 64) * 2048 + kvn + ck * 8);
            vreg3 = *(const u16x8*)(Vt + (size_t)(vd + 96) * 2048 + kvn + ck * 8);
        }

        const unsigned short* Ksc = &Ks[cur][0];
        const unsigned short* Vsc = &Vs[cur][0];

        // ---- swapped QK^T: sc[m2][n] = S^T, lane holds q=w32+m2*16+c, kv=n*16+g*4+j ----
        f32x4 sc[2][4];
        #pragma unroll
        for (int m2 = 0; m2 < 2; ++m2)
            #pragma unroll
            for (int n = 0; n < 4; ++n)
                sc[m2][n] = f32x4{0.f, 0.f, 0.f, 0.f};
        #pragma unroll
        for (int kd = 0; kd < 4; ++kd) {
            bf16x8 bk[4];
            #pragma unroll
            for (int n = 0; n < 4; ++n)
                bk[n] = *(const bf16x8*)(&Ksc[(n * 16 + c) * 128 + ((kd * 32 + g * 8) ^ cswz)]);
            #pragma unroll
            for (int m2 = 0; m2 < 2; ++m2)
                #pragma unroll
                for (int n = 0; n < 4; ++n)
                    sc[m2][n] = __builtin_amdgcn_mfma_f32_16x16x32_bf16(bk[n], aq[m2][kd], sc[m2][n], 0, 0, 0);
        }

        // ---- softmax: in-register row reduce + 2 shuffles; defer-max (T13) ----
        const bool need_mask = (kv0 + 63 > lim_min);
        #pragma unroll
        for (int m2 = 0; m2 < 2; ++m2) {
            if (need_mask) {
                const int lim = lim_min + m2 * 16 + c;
                #pragma unroll
                for (int n = 0; n < 4; ++n)
                    #pragma unroll
                    for (int j = 0; j < 4; ++j)
                        if (kv0 + n * 16 + g * 4 + j > lim) sc[m2][n][j] = -1e30f;
            }
            float rmax = sc[m2][0][0];
            #pragma unroll
            for (int n = 0; n < 4; ++n)
                #pragma unroll
                for (int j = 0; j < 4; ++j)
                    rmax = fmaxf(rmax, sc[m2][n][j]);
            rmax = fmaxf(rmax, __shfl_xor(rmax, 16));
            rmax = fmaxf(rmax, __shfl_xor(rmax, 32));

            if (!__all(rmax <= mrow[m2] + 8.0f)) {
                const float mnew = fmaxf(mrow[m2], rmax);
                const float fs = exp2f(mrow[m2] - mnew);
                mrow[m2] = mnew;
                lrow[m2] *= fs;
                #pragma unroll
                for (int j = 0; j < 4; ++j) {
                    const float fsj = __shfl(fs, (lane & 48) | (g * 4 + j));
                    #pragma unroll
                    for (int nf = 0; nf < 8; ++nf)
                        od[m2][nf][j] *= fsj;
                }
            }
            const float mm = mrow[m2];
            float rsum = 0.f;
            #pragma unroll
            for (int n = 0; n < 4; ++n)
                #pragma unroll
                for (int j = 0; j < 4; ++j) {
                    float p = exp2f(sc[m2][n][j] - mm);
                    sc[m2][n][j] = p;
                    rsum += p;
                }
            rsum += __shfl_xor(rsum, 16);
            rsum += __shfl_xor(rsum, 32);
            lrow[m2] += rsum;
        }

        // ---- write V(t+1) into other buffer (auto vmcnt wait on vregs) ----
        if (next) {
            unsigned short* Vn = &Vs[cur ^ 1][0];
            #pragma unroll
            for (int r = 0; r < 4; ++r) {
                const int d = vd + r * 32;
                const int sw = (d & 7) << 3;
                unsigned short* row = &Vn[d * 64];
                u16x8 vv = r == 0 ? vreg0 : r == 1 ? vreg1 : r == 2 ? vreg2 : vreg3;
                ushort4 lo = { vv[0], vv[1], vv[2], vv[3] };
                ushort4 hi = { vv[4], vv[5], vv[6], vv[7] };
                *(ushort4*)(&row[p0 ^ sw]) = lo;
                *(ushort4*)(&row[p1 ^ sw]) = hi;
            }
        }

        // ---- P -> PV A-frags, lane-local (permutation matches Vs staging) ----
        union PA { u16x8 u; bf16x8 b; };
        PA pa[2][2];
        #pragma unroll
        for (int m2 = 0; m2 < 2; ++m2)
            #pragma unroll
            for (int kk = 0; kk < 2; ++kk)
                #pragma unroll
                for (int e = 0; e < 8; ++e)
                    pa[m2][kk].u[e] = f2bf(sc[m2][2 * kk + (e >> 2)][e & 3]);

        // ---- PV: od += P * V ----
        #pragma unroll
        for (int kk = 0; kk < 2; ++kk) {
            #pragma unroll
            for (int nf = 0; nf < 8; ++nf) {
                bf16x8 bv = *(const bf16x8*)(&Vsc[(nf * 16 + c) * 64 + ((kk * 32 + g * 8) ^ cswz)]);
                od[0][nf] = __builtin_amdgcn_mfma_f32_16x16x32_bf16(pa[0][kk].b, bv, od[0][nf], 0, 0, 0);
                od[1][nf] = __builtin_amdgcn_mfma_f32_16x16x32_bf16(pa[1][kk].b, bv, od[1][nf], 0, 0, 0);
            }
        }

        __syncthreads();
        cur ^= 1;
    }

    // ---- epilogue: normalized partials + (m,l) ----
    const size_t pbase = ((size_t)(half * 64 + bh) * 1024 + qt * 128) * 128;
    const int mlbase = (half * 64 + bh) * 1024 + qt * 128;
    if (lane < 16) {
        #pragma unroll
        for (int m2 = 0; m2 < 2; ++m2) {
            Mp[mlbase + w * 32 + m2 * 16 + c] = mrow[m2];
            Lp[mlbase + w * 32 + m2 * 16 + c] = lrow[m2];
        }
    }
    #pragma unroll
    for (int m2 = 0; m2 < 2; ++m2) {
        #pragma unroll
        for (int j = 0; j < 4; ++j) {
            const float lj = __shfl(lrow[m2], (lane & 48) | (g * 4 + j));
            const float rl = 1.0f / lj;
            const int ql = w * 32 + m2 * 16 + g * 4 + j;
            #pragma unroll
            for (int nf = 0; nf < 8; ++nf)
                Pp[pbase + (size_t)ql * 128 + nf * 16 + c] = f2bf(od[m2][nf][j] * rl);
        }
    }
}

// merge the two KV-split partials -> ctx bf16
__global__ __launch_bounds__(256) void merge_ctx(
    const unsigned short* __restrict__ Pp, const float* __restrict__ Mp,
    const float* __restrict__ Lp, unsigned short* __restrict__ ctx)
{
    const int idx = blockIdx.x * 256 + threadIdx.x;
    const int r = idx >> 4;
    const int dc = (idx & 15) << 3;
    const float m0 = Mp[r], m1 = Mp[65536 + r];
    const float l0 = Lp[r], l1 = Lp[65536 + r];
    const float M = fmaxf(m0, m1);
    float w0 = l0 * exp2f(m0 - M);
    float w1 = l1 * exp2f(m1 - M);
    const float inv = 1.0f / (w0 + w1);
    w0 *= inv; w1 *= inv;
    u16x8 a = *(const u16x8*)(Pp + (size_t)r * 128 + dc);
    u16x8 bb = *(const u16x8*)(Pp + (size_t)8388608 + (size_t)r * 128 + dc);
    const int bh = r >> 10, q = r & 1023;
    unsigned short* dst = ctx + ((size_t)(bh >> 4) * 1024 + q) * 2048 + (bh & 15) * 128 + dc;
    u16x8 outv;
    #pragma unroll
    for (int e = 0; e < 8; ++e)
        outv[e] = f2bf(w0 * bf2f(a[e]) + w1 * bf2f(bb[e]));
    *(u16x8*)dst = outv;
}

// ================= small-ws fallback =================
__global__ __launch_bounds__(256) void copy_cache(
    const float* __restrict__ kc, const float* __restrict__ vc,
    float* __restrict__ kout, float* __restrict__ vout)
{
    size_t i4 = (size_t)blockIdx.x * 256 + threadIdx.x;
    const float* src = blockIdx.y ? vc : kc;
    float* dst = blockIdx.y ? vout : kout;
    size_t e = i4 * 4;
    size_t bh = e >> 17, rem = e & 131071;
    f32x4 v = *(const f32x4*)(src + e);
    *(f32x4*)(dst + (bh << 18) + rem) = v;
}

template<int MODE, bool ABF16>
__global__ __launch_bounds__(256) void gemm_bt(
    const void* __restrict__ Ag, const float* __restrict__ Wf,
    const float* __restrict__ bias, void* __restrict__ dst)
{
    const int tid = threadIdx.x;
    const int lane = tid & 63;
    const int w = tid >> 6;
    const int g = lane >> 4;
    const int c = lane & 15;
    const int wr = w >> 1, wc = w & 1;
    const int m0 = blockIdx.y * 128;
    const int n0 = blockIdx.x * 128;

    __shared__ unsigned short As[128 * 40];
    __shared__ unsigned short Bs[128 * 40];

    f32x4 acc[4][4];
    #pragma unroll
    for (int i = 0; i < 4; ++i)
        #pragma unroll
        for (int j = 0; j < 4; ++j)
            acc[i][j] = f32x4{0.f, 0.f, 0.f, 0.f};

    for (int k0 = 0; k0 < DIMK; k0 += 32) {
        __syncthreads();
        if constexpr (ABF16) {
            const unsigned short* A16 = (const unsigned short*)Ag;
            #pragma unroll
            for (int r = 0; r < 2; ++r) {
                int e8 = r * 256 + tid;
                int row = e8 >> 2, col = (e8 & 3) << 3;
                *(uint4*)(&As[row * 40 + col]) =
                    *(const uint4*)(A16 + (size_t)(m0 + row) * DIMK + k0 + col);
            }
        } else {
            const float* Af = (const float*)Ag;
            #pragma unroll
            for (int r = 0; r < 4; ++r) {
                int e4 = r * 256 + tid;
                int row = e4 >> 3, col = (e4 & 7) << 2;
                f32x4 v = *(const f32x4*)(Af + (size_t)(m0 + row) * DIMK + k0 + col);
                ushort4 pk = { f2bf(v[0]), f2bf(v[1]), f2bf(v[2]), f2bf(v[3]) };
                *(ushort4*)(&As[row * 40 + col]) = pk;
            }
        }
        {
            #pragma unroll
            for (int r = 0; r < 4; ++r) {
                int e4 = r * 256 + tid;
                int row = e4 >> 3, col = (e4 & 7) << 2;
                f32x4 v = *(const f32x4*)(Wf + (size_t)(n0 + row) * DIMK + k0 + col);
                ushort4 pk = { f2bf(v[0]), f2bf(v[1]), f2bf(v[2]), f2bf(v[3]) };
                *(ushort4*)(&Bs[row * 40 + col]) = pk;
            }
        }
        __syncthreads();

        bf16x8 af[4], bfr[4];
        #pragma unroll
        for (int i = 0; i < 4; ++i)
            af[i] = *(const bf16x8*)(&As[(wr * 64 + i * 16 + c) * 40 + g * 8]);
        #pragma unroll
        for (int i = 0; i < 4; ++i)
            bfr[i] = *(const bf16x8*)(&Bs[(wc * 64 + i * 16 + c) * 40 + g * 8]);
        #pragma unroll
        for (int i = 0; i < 4; ++i)
            #pragma unroll
            for (int j = 0; j < 4; ++j)
                acc[i][j] = __builtin_amdgcn_mfma_f32_16x16x32_bf16(af[i], bfr[j], acc[i][j], 0, 0, 0);
    }

    #pragma unroll
    for (int j = 0; j < 4; ++j) {
        const int n = n0 + wc * 64 + j * 16 + c;
        const float bn = bias[n];
        #pragma unroll
        for (int i = 0; i < 4; ++i) {
            float y4[4];
            #pragma unroll
            for (int tq = 0; tq < 4; ++tq) y4[tq] = acc[i][j][tq] + bn;
            const int mb = m0 + wr * 64 + i * 16 + g * 4;
            if constexpr (MODE == 0) {
                #pragma unroll
                for (int tq = 0; tq < 4; ++tq) {
                    int m = mb + tq; int b = m >> 10, s = m & 1023;
                    int hh = n >> 7, d = n & 127;
                    ((unsigned short*)dst)[((((size_t)b * 16 + hh) << 10) + s) * 128 + d] = f2bf(y4[tq] * QSCALE);
                }
            } else if constexpr (MODE == 1) {
                #pragma unroll
                for (int tq = 0; tq < 4; ++tq) {
                    int m = mb + tq; int b = m >> 10, s = m & 1023;
                    int hh = n >> 7, d = n & 127;
                    ((float*)dst)[(((size_t)b * 16 + hh) * 2048 + 1024 + s) * 128 + d] = y4[tq];
                }
            } else {
                #pragma unroll
                for (int tq = 0; tq < 4; ++tq)
                    ((float*)dst)[(size_t)(mb + tq) * 2048 + n] = y4[tq];
            }
        }
    }
}

__global__ __launch_bounds__(256) void attn_stage(
    const unsigned short* __restrict__ Qbf,
    const float* __restrict__ Kf, const float* __restrict__ Vf,
    unsigned short* __restrict__ ctx)
{
    const int qt = blockIdx.x;
    const int bh = blockIdx.y;
    const int b = bh >> 4, h = bh & 15;
    const int tid = threadIdx.x;
    const int lane = tid & 63;
    const int w = tid >> 6;
    const int g = lane >> 4;
    const int c = lane & 15;

    __shared__ unsigned short Ksl[64 * 136];
    __shared__ unsigned short Vtl[128 * 72];
    __shared__ unsigned short Ps[4 * 32 * 72];

    bf16x8 aq[2][4];
    const unsigned short* Qb = Qbf + ((size_t)bh * 1024 + qt * 128) * 128;
    #pragma unroll
    for (int m2 = 0; m2 < 2; ++m2)
        #pragma unroll
        for (int kk = 0; kk < 4; ++kk)
            aq[m2][kk] = *(const bf16x8*)(Qb + (w * 32 + m2 * 16 + c) * 128 + kk * 32 + g * 8);

    f32x4 od[2][8];
    #pragma unroll
    for (int m2 = 0; m2 < 2; ++m2)
        #pragma unroll
        for (int nf = 0; nf < 8; ++nf)
            od[m2][nf] = f32x4{0.f, 0.f, 0.f, 0.f};
    float mrow[2][4], lrow[2][4];
    #pragma unroll
    for (int m2 = 0; m2 < 2; ++m2)
        #pragma unroll
        for (int j = 0; j < 4; ++j) { mrow[m2][j] = -1e30f; lrow[m2][j] = 0.f; }

    const float* Kb = Kf + (size_t)bh * 2048 * 128;
    const float* Vb = Vf + (size_t)bh * 2048 * 128;
    const int ntiles = 18 + 2 * qt;

    for (int t = 0; t < ntiles; ++t) {
        __syncthreads();
        const float* Kt = Kb + (size_t)t * 64 * 128;
        #pragma unroll
        for (int r = 0; r < 8; ++r) {
            int e4 = r * 256 + tid;
            int kv = e4 >> 5, d0 = (e4 & 31) << 2;
            f32x4 v = *(const f32x4*)(Kt + kv * 128 + d0);
            ushort4 pk = { f2bf(v[0]), f2bf(v[1]), f2bf(v[2]), f2bf(v[3]) };
            *(ushort4*)(&Ksl[kv * 136 + d0]) = pk;
        }
        const float* Vg = Vb + (size_t)t * 64 * 128;
        #pragma unroll
        for (int r = 0; r < 8; ++r) {
            int e4 = tid * 8 + r;
            int kv = e4 >> 5, d0 = (e4 & 31) << 2;
            f32x4 v = *(const f32x4*)(Vg + kv * 128 + d0);
            #pragma unroll
            for (int i = 0; i < 4; ++i)
                Vtl[(d0 + i) * 72 + kv] = f2bf(v[i]);
        }
        __syncthreads();

        f32x4 sc[2][4];
        #pragma unroll
        for (int m2 = 0; m2 < 2; ++m2)
            #pragma unroll
            for (int n = 0; n < 4; ++n)
                sc[m2][n] = f32x4{0.f, 0.f, 0.f, 0.f};
        #pragma unroll
        for (int kk = 0; kk < 4; ++kk) {
            bf16x8 bk[4];
            #pragma unroll
            for (int n = 0; n < 4; ++n)
                bk[n] = *(const bf16x8*)(&Ksl[(n * 16 + c) * 136 + kk * 32 + g * 8]);
            #pragma unroll
            for (int m2 = 0; m2 < 2; ++m2)
                #pragma unroll
                for (int n = 0; n < 4; ++n)
                    sc[m2][n] = __builtin_amdgcn_mfma_f32_16x16x32_bf16(aq[m2][kk], bk[n], sc[m2][n], 0, 0, 0);
        }

        const int kvbase = t * 64;
        #pragma unroll
        for (int m2 = 0; m2 < 2; ++m2) {
            #pragma unroll
            for (int j = 0; j < 4; ++j) {
                const int qg = qt * 128 + w * 32 + m2 * 16 + g * 4 + j;
                const int lim = qg + 1024;
                float rmax = -1e30f;
                #pragma unroll
                for (int n = 0; n < 4; ++n) {
                    float s = sc[m2][n][j] * QSCALE;
                    if (kvbase + n * 16 + c > lim) s = -1e30f;
                    sc[m2][n][j] = s;
                    rmax = fmaxf(rmax, s);
                }
                #pragma unroll
                for (int off = 1; off < 16; off <<= 1)
                    rmax = fmaxf(rmax, __shfl_xor(rmax, off));
                float mold = mrow[m2][j];
                float mnew = fmaxf(mold, rmax);
                mrow[m2][j] = mnew;
                float fs = exp2f(mold - mnew);
                float rsum = 0.f;
                #pragma unroll
                for (int n = 0; n < 4; ++n) {
                    float p = exp2f(sc[m2][n][j] - mnew);
                    sc[m2][n][j] = p;
                    rsum += p;
                }
                #pragma unroll
                for (int off = 1; off < 16; off <<= 1)
                    rsum += __shfl_xor(rsum, off);
                lrow[m2][j] = lrow[m2][j] * fs + rsum;
                #pragma unroll
                for (int nf = 0; nf < 8; ++nf)
                    od[m2][nf][j] *= fs;
            }
        }

        unsigned short* Pw = &Ps[w * 32 * 72];
        #pragma unroll
        for (int m2 = 0; m2 < 2; ++m2)
            #pragma unroll
            for (int n = 0; n < 4; ++n)
                #pragma unroll
                for (int j = 0; j < 4; ++j)
                    Pw[(m2 * 16 + g * 4 + j) * 72 + n * 16 + c] = f2bf(sc[m2][n][j]);

        #pragma unroll
        for (int kk = 0; kk < 2; ++kk) {
            bf16x8 ap0 = *(const bf16x8*)(&Ps[(w * 32 + c) * 72 + kk * 32 + g * 8]);
            bf16x8 ap1 = *(const bf16x8*)(&Ps[(w * 32 + 16 + c) * 72 + kk * 32 + g * 8]);
            #pragma unroll
            for (int nf = 0; nf < 8; ++nf) {
                bf16x8 bv = *(const bf16x8*)(&Vtl[(nf * 16 + c) * 72 + kk * 32 + g * 8]);
                od[0][nf] = __builtin_amdgcn_mfma_f32_16x16x32_bf16(ap0, bv, od[0][nf], 0, 0, 0);
                od[1][nf] = __builtin_amdgcn_mfma_f32_16x16x32_bf16(ap1, bv, od[1][nf], 0, 0, 0);
            }
        }
    }

    #pragma unroll
    for (int m2 = 0; m2 < 2; ++m2) {
        #pragma unroll
        for (int j = 0; j < 4; ++j) {
            const int qg = qt * 128 + w * 32 + m2 * 16 + g * 4 + j;
            const float rl = 1.0f / lrow[m2][j];
            #pragma unroll
            for (int nf = 0; nf < 8; ++nf) {
                const int d = nf * 16 + c;
                ctx[((size_t)b * 1024 + qg) * 2048 + h * 128 + d] = f2bf(od[m2][nf][j] * rl);
            }
        }
    }
}

extern "C" void kernel_launch(void* const* d_in, const int* in_sizes, int n_in,
                              void* d_out, int out_size, void* d_ws, size_t ws_size,
                              hipStream_t stream) {
    const float* x  = (const float*)d_in[0];
    const float* kc = (const float*)d_in[1];
    const float* vc = (const float*)d_in[2];
    const float* Wq = (const float*)d_in[3];
    const float* bq = (const float*)d_in[4];
    const float* Wk = (const float*)d_in[5];
    const float* bk = (const float*)d_in[6];
    const float* Wv = (const float*)d_in[7];
    const float* bv = (const float*)d_in[8];
    const float* Wo = (const float*)d_in[9];
    const float* bo = (const float*)d_in[10];

    float* outp = (float*)d_out;
    float* kout = outp + (size_t)8388608;
    float* vout = outp + (size_t)25165824;

    unsigned short* Qbf = (unsigned short*)d_ws;          //  8,388,608
    unsigned short* ctx = Qbf + (size_t)8388608;          //  8,388,608
    unsigned short* Kbf = ctx + (size_t)8388608;          // 16,777,216
    unsigned short* Vtb = Kbf + (size_t)16777216;         // 16,777,216
    unsigned short* xbf = Vtb + (size_t)16777216;         //  8,388,608
    unsigned short* Wqb = xbf + (size_t)8388608;
    unsigned short* Wkb = Wqb + (size_t)4194304;
    unsigned short* Wvb = Wkb + (size_t)4194304;
    unsigned short* Wob = Wvb + (size_t)4194304;
    unsigned short* Pp = xbf;                             // reuse xbf+Wqb+Wkb
    float* Mp = (float*)Wvb;
    float* Lp = Mp + (size_t)131072;

    const bool full = ws_size >= (size_t)150994944;

    if (full) {
        conv_all<<<24576, 256, 0, stream>>>(x, Wq, Wk, Wv, Wo, xbf, Wqb, Wkb, Wvb, Wob);
        k_dual<<<8192, 256, 0, stream>>>(kc, kout, Kbf);
        v_dual<<<dim3(16, 64), 256, 0, stream>>>(vc, vout, Vtb);
        gemm_qkv<<<1536, 256, 0, stream>>>(xbf, Wqb, Wkb, Wvb, bq, bk, bv,
                                           Qbf, kout, Kbf, vout, Vtb);
        attn5<<<1024, 256, 0, stream>>>(Qbf, Kbf, Vtb, Pp, Mp, Lp);
        merge_ctx<<<4096, 256, 0, stream>>>(Pp, Mp, Lp, ctx);
        gemm_wo<<<512, 256, 0, stream>>>(ctx, Wob, bo, outp);
    } else {
        copy_cache<<<dim3(8192, 2), 256, 0, stream>>>(kc, vc, kout, vout);
        gemm_bt<0, false><<<dim3(16, 32), 256, 0, stream>>>(x, Wq, bq, Qbf);
        gemm_bt<1, false><<<dim3(16, 32), 256, 0, stream>>>(x, Wk, bk, kout);
        gemm_bt<1, false><<<dim3(16, 32), 256, 0, stream>>>(x, Wv, bv, vout);
        attn_stage<<<dim3(8, 64), 256, 0, stream>>>(Qbf, kout, vout, ctx);
        gemm_bt<2, true><<<dim3(16, 32), 256, 0, stream>>>(ctx, Wo, bo, outp);
    }
}